// Round 5
// baseline (364.084 us; speedup 1.0000x reference)
//
#include <hip/hip_runtime.h>

#define N_NODES 5000
#define N_EDGES 160000
#define BATCH 2
#define TSTEPS 12
#define ROWS (BATCH*N_NODES)   // 10000
#define RB 16                  // rows per block
#define NRB (ROWS/RB)          // 625

typedef short short8_t __attribute__((ext_vector_type(8)));
typedef unsigned short ushort8_t __attribute__((ext_vector_type(8)));
typedef float f32x4 __attribute__((ext_vector_type(4)));

__device__ inline unsigned short f2bf(float f){
  union { float f; unsigned u; } v; v.f = f;
  unsigned r = v.u + 0x7fff + ((v.u >> 16) & 1);   // RNE
  return (unsigned short)(r >> 16);
}
__device__ inline float bf2f(unsigned short s){
  union { unsigned u; float f; } v; v.u = ((unsigned)s) << 16;
  return v.f;
}

// ---------------- k1: edge-degree count (blocks 0..624) + WF fragments (625..640) + bias (641) ----------------
// WF[ (kt4*16+ct)*1024 + hl*512 + lane*8 + j ], kt4 = which*2+kt in 0..3
//   value = W[col][k], col = ct*16+(lane&15), k = kt*32+(lane>>4)*8+j
__global__ void k1(const int* __restrict__ ei, int* __restrict__ cnt,
                   const float* __restrict__ W_ih, const float* __restrict__ W_hh,
                   const float* __restrict__ b_ih, const float* __restrict__ b_hh,
                   const float* __restrict__ b2,
                   unsigned short* __restrict__ WF, float* __restrict__ biasT) {
  int bid = blockIdx.x;
  if (bid < 625) {
    int e = bid*256 + threadIdx.x;
    if (e < N_EDGES) atomicAdd(&cnt[ei[N_EDGES + e]], 1);
    return;
  }
  bid -= 625;
  if (bid == 16) {
    int j = threadIdx.x;
    float s = b_ih[j] + b_hh[j];
    for (int k=0;k<64;k++) s = fmaf(b2[k], W_ih[j*64+k], s);
    biasT[j] = s;
    return;
  }
  int idx = bid*256 + threadIdx.x;    // 0..4095
  int lane  = idx & 63;
  int ct    = (idx >> 6) & 15;
  int kt    = (idx >> 10) & 1;
  int which = idx >> 11;
  const float* W = which ? W_hh : W_ih;
  int col = ct*16 + (lane & 15);
  int k0  = kt*32 + (lane >> 4)*8;
  size_t base = ((size_t)((which*2+kt)*16 + ct))*1024 + (size_t)lane*8;
  #pragma unroll
  for (int j=0;j<8;j++){
    float w = W[col*64 + k0 + j];
    unsigned short hi = f2bf(w);
    unsigned short lo = f2bf(w - bf2f(hi));
    WF[base + j]       = hi;
    WF[base + 512 + j] = lo;
  }
}

__global__ void k_scan(const int* __restrict__ cnt, int* __restrict__ row_ptr,
                       float* __restrict__ dinv) {
  __shared__ int sums[1024];
  int tid = threadIdx.x;
  constexpr int C = (N_NODES + 1023)/1024; // 5
  int base = tid*C;
  int local[C];
  int s = 0;
  #pragma unroll
  for (int i=0;i<C;i++){ int idx=base+i; int v=(idx<N_NODES)?cnt[idx]:0; local[i]=s; s+=v; }
  sums[tid]=s; __syncthreads();
  for (int off=1; off<1024; off<<=1) {
    int v = sums[tid];
    int add = (tid>=off)? sums[tid-off]:0;
    __syncthreads();
    sums[tid] = v + add;
    __syncthreads();
  }
  int excl = (tid>0)? sums[tid-1]:0;
  #pragma unroll
  for (int i=0;i<C;i++){ int idx=base+i; if(idx<N_NODES) row_ptr[idx]=excl+local[i]; }
  if (tid==0) row_ptr[N_NODES] = sums[1023];
  #pragma unroll
  for (int i=0;i<C;i++){ int idx=base+i; if(idx<N_NODES) dinv[idx]=rsqrtf((float)(cnt[idx]+1)); }
}

// ---------------- k2: CSR fill (blocks 0..624) + xdT build (625..1249) ----------------
// xdT[n][c] = x[c*N + n] * dinv[n] for c<24 (c = b*12+t), 0 for pad c in 24..31
__global__ void k2(const int* __restrict__ ei, const int* __restrict__ row_ptr,
                   int* __restrict__ fill, int* __restrict__ csr_src,
                   const float* __restrict__ x, const float* __restrict__ dinv,
                   float* __restrict__ xdT) {
  int bid = blockIdx.x;
  if (bid < 625) {
    int e = bid*256 + threadIdx.x;
    if (e < N_EDGES) {
      int src = ei[e], dst = ei[N_EDGES+e];
      int pos = row_ptr[dst] + atomicAdd(&fill[dst],1);
      csr_src[pos] = src;
    }
    return;
  }
  int i = (bid-625)*256 + threadIdx.x;   // 0..159999 = 5000*32
  int n = i >> 5, c = i & 31;
  xdT[i] = (c < 24) ? x[c*N_NODES + n] * dinv[n] : 0.f;
}

// ---------------- k_p: P[n][tb] = dinv[n]*(sum_src xdT[src][tb] + xdT[n][tb]), all 24 tb at once ----------------
__global__ void __launch_bounds__(256) k_p(
    const float* __restrict__ xdT,
    const int* __restrict__ row_ptr, const int* __restrict__ csr_src,
    const float* __restrict__ dinv, float* __restrict__ P)
{
  int tid = threadIdx.x;
  int wv = tid >> 6, lane = tid & 63;
  int s8 = lane >> 3, g8 = lane & 7;        // 8 edge-slots x 8 col-groups (float4)
  #pragma unroll
  for (int i=0;i<4;i++){
    int n = blockIdx.x*RB + wv*4 + i;
    if (n >= N_NODES) continue;
    int e0 = row_ptr[n], e1 = row_ptr[n+1];
    float ax=0.f, ay=0.f, az=0.f, aw=0.f;
    int e = e0 + s8;
    for (; e + 8 < e1; e += 16){
      int i1 = csr_src[e], i2 = csr_src[e+8];
      float4 v1 = *(const float4*)&xdT[i1*32 + g8*4];
      float4 v2 = *(const float4*)&xdT[i2*32 + g8*4];
      ax += v1.x + v2.x; ay += v1.y + v2.y;
      az += v1.z + v2.z; aw += v1.w + v2.w;
    }
    if (e < e1){
      int i1 = csr_src[e];
      float4 v1 = *(const float4*)&xdT[i1*32 + g8*4];
      ax += v1.x; ay += v1.y; az += v1.z; aw += v1.w;
    }
    #pragma unroll
    for (int m=8; m<=32; m<<=1){
      ax += __shfl_xor(ax, m, 64); ay += __shfl_xor(ay, m, 64);
      az += __shfl_xor(az, m, 64); aw += __shfl_xor(aw, m, 64);
    }
    if (s8 == 0){
      float4 sv = *(const float4*)&xdT[n*32 + g8*4];
      float dn = dinv[n];
      float4 o;
      o.x = dn*(ax + sv.x); o.y = dn*(ay + sv.y);
      o.z = dn*(az + sv.z); o.w = dn*(aw + sv.w);
      *(float4*)&P[n*32 + g8*4] = o;
    }
  }
}

// ---------------- k_hw2: hw2d[flat][lane] = bf16( dinv[n] * relu(p*W1+b1) @ W2 ), flat=(t*2+b)*N+n ----------------
__global__ void __launch_bounds__(256) k_hw2(
    const float* __restrict__ P, const float* __restrict__ dinv,
    const float* __restrict__ W1, const float* __restrict__ b1,
    const float* __restrict__ W2, unsigned short* __restrict__ hw2d)
{
  __shared__ float sW2[4096];
  __shared__ float sW1[64], sb1[64];
  int tid = threadIdx.x;
  for (int i = tid; i < 4096; i += 256) sW2[i] = W2[i];
  if (tid < 64) { sW1[tid] = W1[tid]; sb1[tid] = b1[tid]; }
  __syncthreads();
  int wv = tid >> 6, lane = tid & 63;
  float p[4], dn[4];
  int fl[4];
  #pragma unroll
  for (int i=0;i<4;i++){
    int flat = blockIdx.x*RB + wv*4 + i;      // 0..119999
    int sl = flat / N_NODES;                   // t*2+b
    int n  = flat - sl*N_NODES;
    int b  = sl & 1, t = sl >> 1;
    p[i]  = P[n*32 + b*12 + t];
    dn[i] = dinv[n];
    fl[i] = flat;
  }
  float a[4] = {0.f,0.f,0.f,0.f};
  #pragma unroll 8
  for (int k=0;k<64;k++){
    float w2 = sW2[k*64 + lane];
    float w1 = sW1[k], bk = sb1[k];
    #pragma unroll
    for (int i=0;i<4;i++)
      a[i] = fmaf(fmaxf(fmaf(p[i], w1, bk), 0.f), w2, a[i]);
  }
  #pragma unroll
  for (int i=0;i<4;i++)
    hw2d[(size_t)fl[i]*64 + lane] = f2bf(dn[i]*a[i]);
}

// ---------------- k_lstm: per t { aggregate bf16 hw2d -> sA; MFMA [agg|h]@[Wih;Whh]; LSTM update } ----------------
__global__ void __launch_bounds__(256) k_lstm(
    const unsigned short* __restrict__ hw2d,
    const int* __restrict__ row_ptr, const int* __restrict__ csr_src,
    const float* __restrict__ dinv,
    const unsigned short* __restrict__ WF,   // 4 kt-tiles: 0,1=W_ih  2,3=W_hh
    const float* __restrict__ biasT,
    const float* __restrict__ fc_w, const float* __restrict__ fc_b,
    float* __restrict__ out)
{
  __shared__ float sA[RB*68];             // agg rows [16][64], stride 68
  __shared__ unsigned short sHh[RB*72];   // h hi bf16
  __shared__ unsigned short sHl[RB*72];   // h lo bf16
  __shared__ float sG[RB*260];            // gates [16][256+4]
  int tid = threadIdx.x;
  int r0 = blockIdx.x*RB;
  int wv = tid >> 6, lane = tid & 63;
  int row = lane & 15, kg = lane >> 4;
  int urow = tid >> 4, uc0 = (tid & 15)*4;
  int s8 = lane >> 3, g8 = lane & 7;      // agg: 8 edge-slots x 8 col-groups (ushort8)

  // per-row constants for the aggregation (rows wv*4..wv*4+3)
  int nn[4], ee0[4], ee1[4], bo[4];
  float dnn[4];
  #pragma unroll
  for (int i=0;i<4;i++){
    int r = r0 + wv*4 + i;
    int b = (r >= N_NODES) ? 1 : 0;
    int n = r - b*N_NODES;
    nn[i] = n; bo[i] = b*(N_NODES*64);
    ee0[i] = row_ptr[n]; ee1[i] = row_ptr[n+1];
    dnn[i] = dinv[n];
  }

  float creg[4] = {0.f,0.f,0.f,0.f};
  float hn[4]   = {0.f,0.f,0.f,0.f};

  for (int t=0; t<TSTEPS; ++t){
    const unsigned short* hwt = hw2d + (size_t)t*(BATCH*N_NODES*64);
    // ---- phase 1: aggregate into sA ----
    #pragma unroll
    for (int i=0;i<4;i++){
      int lr = wv*4 + i;
      const unsigned short* hwb = hwt + bo[i];
      float a0=0,a1=0,a2=0,a3=0,a4=0,a5=0,a6=0,a7=0;
      int e = ee0[i] + s8;
      int e1 = ee1[i];
      for (; e + 8 < e1; e += 16){
        int i1 = csr_src[e], i2 = csr_src[e+8];
        ushort8_t v1 = *(const ushort8_t*)(hwb + i1*64 + g8*8);
        ushort8_t v2 = *(const ushort8_t*)(hwb + i2*64 + g8*8);
        a0 += bf2f(v1[0]) + bf2f(v2[0]); a1 += bf2f(v1[1]) + bf2f(v2[1]);
        a2 += bf2f(v1[2]) + bf2f(v2[2]); a3 += bf2f(v1[3]) + bf2f(v2[3]);
        a4 += bf2f(v1[4]) + bf2f(v2[4]); a5 += bf2f(v1[5]) + bf2f(v2[5]);
        a6 += bf2f(v1[6]) + bf2f(v2[6]); a7 += bf2f(v1[7]) + bf2f(v2[7]);
      }
      if (e < e1){
        int i1 = csr_src[e];
        ushort8_t v1 = *(const ushort8_t*)(hwb + i1*64 + g8*8);
        a0 += bf2f(v1[0]); a1 += bf2f(v1[1]); a2 += bf2f(v1[2]); a3 += bf2f(v1[3]);
        a4 += bf2f(v1[4]); a5 += bf2f(v1[5]); a6 += bf2f(v1[6]); a7 += bf2f(v1[7]);
      }
      #pragma unroll
      for (int m=8; m<=32; m<<=1){
        a0 += __shfl_xor(a0, m, 64); a1 += __shfl_xor(a1, m, 64);
        a2 += __shfl_xor(a2, m, 64); a3 += __shfl_xor(a3, m, 64);
        a4 += __shfl_xor(a4, m, 64); a5 += __shfl_xor(a5, m, 64);
        a6 += __shfl_xor(a6, m, 64); a7 += __shfl_xor(a7, m, 64);
      }
      if (s8 == 0){
        ushort8_t sv = *(const ushort8_t*)(hwb + nn[i]*64 + g8*8);
        float dn = dnn[i];
        float4 o0, o1;
        o0.x = dn*(a0 + bf2f(sv[0])); o0.y = dn*(a1 + bf2f(sv[1]));
        o0.z = dn*(a2 + bf2f(sv[2])); o0.w = dn*(a3 + bf2f(sv[3]));
        o1.x = dn*(a4 + bf2f(sv[4])); o1.y = dn*(a5 + bf2f(sv[5]));
        o1.z = dn*(a6 + bf2f(sv[6])); o1.w = dn*(a7 + bf2f(sv[7]));
        *(float4*)&sA[lr*68 + g8*8]     = o0;
        *(float4*)&sA[lr*68 + g8*8 + 4] = o1;
      }
    }
    __syncthreads();

    // ---- phase 2: MFMA ----
    short8_t Ah[2], Al[2];
    #pragma unroll
    for (int kt=0; kt<2; kt++){
      const float* ap = &sA[row*68 + kt*32 + kg*8];
      float4 x0 = *(const float4*)ap;
      float4 x1 = *(const float4*)(ap + 4);
      float xs[8] = {x0.x,x0.y,x0.z,x0.w,x1.x,x1.y,x1.z,x1.w};
      #pragma unroll
      for (int j=0;j<8;j++){
        unsigned short h = f2bf(xs[j]);
        Ah[kt][j] = (short)h;
        Al[kt][j] = (short)f2bf(xs[j] - bf2f(h));
      }
    }
    short8_t Hh[2], Hl[2];
    if (t > 0){
      #pragma unroll
      for (int kt=0; kt<2; kt++){
        int hoff = row*72 + kt*32 + kg*8;
        Hh[kt] = *(const short8_t*)&sHh[hoff];
        Hl[kt] = *(const short8_t*)&sHl[hoff];
      }
    }
    f32x4 acc[4];
    #pragma unroll
    for (int i=0;i<4;i++){
      float bs = biasT[(wv*4+i)*16 + row];
      acc[i][0]=bs; acc[i][1]=bs; acc[i][2]=bs; acc[i][3]=bs;
    }
    #pragma unroll
    for (int i=0;i<4;i++){
      int ct = wv*4 + i;
      f32x4 a = acc[i];
      #pragma unroll
      for (int kt=0; kt<2; kt++){
        size_t base = ((size_t)(kt*16 + ct))*1024 + (size_t)lane*8;
        short8_t bh = *(const short8_t*)(WF + base);
        short8_t bl = *(const short8_t*)(WF + base + 512);
        a = __builtin_amdgcn_mfma_f32_16x16x32_bf16(Ah[kt], bh, a, 0, 0, 0);
        a = __builtin_amdgcn_mfma_f32_16x16x32_bf16(Ah[kt], bl, a, 0, 0, 0);
        a = __builtin_amdgcn_mfma_f32_16x16x32_bf16(Al[kt], bh, a, 0, 0, 0);
      }
      if (t > 0){
        #pragma unroll
        for (int kt=0; kt<2; kt++){
          size_t base = ((size_t)((2+kt)*16 + ct))*1024 + (size_t)lane*8;
          short8_t bh = *(const short8_t*)(WF + base);
          short8_t bl = *(const short8_t*)(WF + base + 512);
          a = __builtin_amdgcn_mfma_f32_16x16x32_bf16(Hh[kt], bh, a, 0, 0, 0);
          a = __builtin_amdgcn_mfma_f32_16x16x32_bf16(Hh[kt], bl, a, 0, 0, 0);
          a = __builtin_amdgcn_mfma_f32_16x16x32_bf16(Hl[kt], bh, a, 0, 0, 0);
        }
      }
      acc[i] = a;
    }
    #pragma unroll
    for (int i=0;i<4;i++){
      int col = (wv*4+i)*16 + row;
      #pragma unroll
      for (int rr=0;rr<4;rr++)
        sG[(kg*4+rr)*260 + col] = acc[i][rr];
    }
    __syncthreads();

    // ---- phase 3: LSTM update ----
    {
      float4 gi = *(const float4*)&sG[urow*260 + uc0];
      float4 gf = *(const float4*)&sG[urow*260 + 64  + uc0];
      float4 gg = *(const float4*)&sG[urow*260 + 128 + uc0];
      float4 go = *(const float4*)&sG[urow*260 + 192 + uc0];
      float gis[4] = {gi.x,gi.y,gi.z,gi.w};
      float gfs[4] = {gf.x,gf.y,gf.z,gf.w};
      float ggs[4] = {gg.x,gg.y,gg.z,gg.w};
      float gos[4] = {go.x,go.y,go.z,go.w};
      unsigned short hh[4], hl[4];
      #pragma unroll
      for (int j=0;j<4;j++){
        float si = 1.f/(1.f + __expf(-gis[j]));
        float sf = 1.f/(1.f + __expf(-gfs[j]));
        float so = 1.f/(1.f + __expf(-gos[j]));
        float tg = tanhf(ggs[j]);
        float cn = sf*creg[j] + si*tg;
        creg[j] = cn;
        hn[j] = so*tanhf(cn);
        hh[j] = f2bf(hn[j]);
        hl[j] = f2bf(hn[j] - bf2f(hh[j]));
      }
      unsigned w0 = (unsigned)hh[0] | ((unsigned)hh[1] << 16);
      unsigned w1 = (unsigned)hh[2] | ((unsigned)hh[3] << 16);
      unsigned v0 = (unsigned)hl[0] | ((unsigned)hl[1] << 16);
      unsigned v1 = (unsigned)hl[2] | ((unsigned)hl[3] << 16);
      *(uint2*)&sHh[urow*72 + uc0] = make_uint2(w0, w1);
      *(uint2*)&sHl[urow*72 + uc0] = make_uint2(v0, v1);
    }
    __syncthreads();
  }
  // final projection
  float4 fw = *(const float4*)&fc_w[uc0];
  float v = hn[0]*fw.x + hn[1]*fw.y + hn[2]*fw.z + hn[3]*fw.w;
  v += __shfl_xor(v, 1, 64);
  v += __shfl_xor(v, 2, 64);
  v += __shfl_xor(v, 4, 64);
  v += __shfl_xor(v, 8, 64);
  if ((lane & 15) == 0) out[r0 + urow] = v + fc_b[0];
}

extern "C" void kernel_launch(void* const* d_in, const int* in_sizes, int n_in,
                              void* d_out, int out_size, void* d_ws, size_t ws_size,
                              hipStream_t stream) {
  const float* x    = (const float*)d_in[0];
  const int*   ei   = (const int*)d_in[1];
  const float* W1   = (const float*)d_in[2];
  const float* b1   = (const float*)d_in[3];
  const float* W2   = (const float*)d_in[4];
  const float* b2   = (const float*)d_in[5];
  const float* W_ih = (const float*)d_in[6];
  const float* W_hh = (const float*)d_in[7];
  const float* b_ih = (const float*)d_in[8];
  const float* b_hh = (const float*)d_in[9];
  const float* fc_w = (const float*)d_in[10];
  const float* fc_b = (const float*)d_in[11];
  float* out = (float*)d_out;

  char* ws = (char*)d_ws;
  size_t off = 0;
  auto alloc = [&](size_t bytes)->void* { void* p = ws + off; off += (bytes + 255) & ~255ul; return p; };
  float*          dinv    = (float*)alloc(N_NODES*4);
  int*            cntfill = (int*)alloc(2*N_NODES*4);      // [0:N)=cnt, [N:2N)=fill
  int*            row_ptr = (int*)alloc((N_NODES+1)*4);
  int*            csr_src = (int*)alloc(N_EDGES*4);
  unsigned short* WF      = (unsigned short*)alloc(2*2*16*1024*2);  // 128 KB
  float*          biasT   = (float*)alloc(256*4);
  float*          xdT     = (float*)alloc((size_t)N_NODES*32*4);    // 640 KB
  float*          P       = (float*)alloc((size_t)N_NODES*32*4);    // 640 KB
  unsigned short* hw2d    = (unsigned short*)alloc((size_t)TSTEPS*BATCH*N_NODES*64*2); // 15.4 MB

  int* cnt  = cntfill;
  int* fill = cntfill + N_NODES;

  hipMemsetAsync(cntfill, 0, 2*N_NODES*4, stream);

  k1    <<<642, 256, 0, stream>>>(ei, cnt, W_ih, W_hh, b_ih, b_hh, b2, WF, biasT);
  k_scan<<<1, 1024, 0, stream>>>(cnt, row_ptr, dinv);
  k2    <<<1250, 256, 0, stream>>>(ei, row_ptr, fill, csr_src, x, dinv, xdT);
  k_p   <<<(N_NODES+RB-1)/RB, 256, 0, stream>>>(xdT, row_ptr, csr_src, dinv, P);
  k_hw2 <<<TSTEPS*BATCH*N_NODES/RB, 256, 0, stream>>>(P, dinv, W1, b1, W2, hw2d);
  k_lstm<<<NRB, 256, 0, stream>>>(hw2d, row_ptr, csr_src, dinv, WF, biasT, fc_w, fc_b, out);
}

// Round 6
// 183.055 us; speedup vs baseline: 1.9889x; 1.9889x over previous
//
#include <hip/hip_runtime.h>

#define N_NODES 5000
#define N_EDGES 160000
#define BATCH 2
#define TSTEPS 12
#define ROWS (BATCH*N_NODES)   // 10000
#define RB 16                  // rows per block
#define NRB (ROWS/RB)          // 625

typedef short short8_t __attribute__((ext_vector_type(8)));
typedef unsigned short ushort8_t __attribute__((ext_vector_type(8)));
typedef float f32x4 __attribute__((ext_vector_type(4)));

__device__ inline unsigned short f2bf(float f){
  union { float f; unsigned u; } v; v.f = f;
  unsigned r = v.u + 0x7fff + ((v.u >> 16) & 1);   // RNE
  return (unsigned short)(r >> 16);
}
__device__ inline float bf2f(unsigned short s){
  union { unsigned u; float f; } v; v.u = ((unsigned)s) << 16;
  return v.f;
}

// Bijective XCD swizzle for grid 3750 = 6*469 + 2*468 (gid = i*8 + xcd)
__device__ inline int swz3750(int gid){
  int xcd = gid & 7, i = gid >> 3;
  return (xcd < 6 ? xcd*469 + i : 6*469 + (xcd-6)*468 + i);
}

// ---------------- k1: edge-degree count (blocks 0..624) + WF fragments (625..640) + bias (641) ----------------
// WF[ (kt4*16+ct)*1024 + hl*512 + lane*8 + j ], kt4 = which*2+kt in 0..3
//   value = W[col][k], col = ct*16+(lane&15), k = kt*32+(lane>>4)*8+j
__global__ void k1(const int* __restrict__ ei, int* __restrict__ cnt,
                   const float* __restrict__ W_ih, const float* __restrict__ W_hh,
                   const float* __restrict__ b_ih, const float* __restrict__ b_hh,
                   const float* __restrict__ b2,
                   unsigned short* __restrict__ WF, float* __restrict__ biasT) {
  int bid = blockIdx.x;
  if (bid < 625) {
    int e = bid*256 + threadIdx.x;
    if (e < N_EDGES) atomicAdd(&cnt[ei[N_EDGES + e]], 1);
    return;
  }
  bid -= 625;
  if (bid == 16) {
    int j = threadIdx.x;
    float s = b_ih[j] + b_hh[j];
    for (int k=0;k<64;k++) s = fmaf(b2[k], W_ih[j*64+k], s);
    biasT[j] = s;
    return;
  }
  int idx = bid*256 + threadIdx.x;    // 0..4095
  int lane  = idx & 63;
  int ct    = (idx >> 6) & 15;
  int kt    = (idx >> 10) & 1;
  int which = idx >> 11;
  const float* W = which ? W_hh : W_ih;
  int col = ct*16 + (lane & 15);
  int k0  = kt*32 + (lane >> 4)*8;
  size_t base = ((size_t)((which*2+kt)*16 + ct))*1024 + (size_t)lane*8;
  #pragma unroll
  for (int j=0;j<8;j++){
    float w = W[col*64 + k0 + j];
    unsigned short hi = f2bf(w);
    unsigned short lo = f2bf(w - bf2f(hi));
    WF[base + j]       = hi;
    WF[base + 512 + j] = lo;
  }
}

__global__ void k_scan(const int* __restrict__ cnt, int* __restrict__ row_ptr,
                       float* __restrict__ dinv) {
  __shared__ int sums[1024];
  int tid = threadIdx.x;
  constexpr int C = (N_NODES + 1023)/1024; // 5
  int base = tid*C;
  int local[C];
  int s = 0;
  #pragma unroll
  for (int i=0;i<C;i++){ int idx=base+i; int v=(idx<N_NODES)?cnt[idx]:0; local[i]=s; s+=v; }
  sums[tid]=s; __syncthreads();
  for (int off=1; off<1024; off<<=1) {
    int v = sums[tid];
    int add = (tid>=off)? sums[tid-off]:0;
    __syncthreads();
    sums[tid] = v + add;
    __syncthreads();
  }
  int excl = (tid>0)? sums[tid-1]:0;
  #pragma unroll
  for (int i=0;i<C;i++){ int idx=base+i; if(idx<N_NODES) row_ptr[idx]=excl+local[i]; }
  if (tid==0) row_ptr[N_NODES] = sums[1023];
  #pragma unroll
  for (int i=0;i<C;i++){ int idx=base+i; if(idx<N_NODES) dinv[idx]=rsqrtf((float)(cnt[idx]+1)); }
}

// ---------------- k2: CSR fill (blocks 0..624) + xdT build (625..1249) ----------------
// xdT[n][c] = x[c*N + n] * dinv[n] for c<24 (c = b*12+t), 0 for pad c in 24..31
__global__ void k2(const int* __restrict__ ei, const int* __restrict__ row_ptr,
                   int* __restrict__ fill, int* __restrict__ csr_src,
                   const float* __restrict__ x, const float* __restrict__ dinv,
                   float* __restrict__ xdT) {
  int bid = blockIdx.x;
  if (bid < 625) {
    int e = bid*256 + threadIdx.x;
    if (e < N_EDGES) {
      int src = ei[e], dst = ei[N_EDGES+e];
      int pos = row_ptr[dst] + atomicAdd(&fill[dst],1);
      csr_src[pos] = src;
    }
    return;
  }
  int i = (bid-625)*256 + threadIdx.x;   // 0..159999 = 5000*32
  int n = i >> 5, c = i & 31;
  xdT[i] = (c < 24) ? x[c*N_NODES + n] * dinv[n] : 0.f;
}

// ---------------- k_p: P[n][tb] = dinv[n]*(sum_src xdT[src][tb] + xdT[n][tb]), all 24 tb at once ----------------
__global__ void __launch_bounds__(256) k_p(
    const float* __restrict__ xdT,
    const int* __restrict__ row_ptr, const int* __restrict__ csr_src,
    const float* __restrict__ dinv, float* __restrict__ P)
{
  int tid = threadIdx.x;
  int wv = tid >> 6, lane = tid & 63;
  int s8 = lane >> 3, g8 = lane & 7;        // 8 edge-slots x 8 col-groups (float4)
  #pragma unroll
  for (int i=0;i<4;i++){
    int n = blockIdx.x*RB + wv*4 + i;
    if (n >= N_NODES) continue;
    int e0 = row_ptr[n], e1 = row_ptr[n+1];
    float ax=0.f, ay=0.f, az=0.f, aw=0.f;
    int e = e0 + s8;
    for (; e + 8 < e1; e += 16){
      int i1 = csr_src[e], i2 = csr_src[e+8];
      float4 v1 = *(const float4*)&xdT[i1*32 + g8*4];
      float4 v2 = *(const float4*)&xdT[i2*32 + g8*4];
      ax += v1.x + v2.x; ay += v1.y + v2.y;
      az += v1.z + v2.z; aw += v1.w + v2.w;
    }
    if (e < e1){
      int i1 = csr_src[e];
      float4 v1 = *(const float4*)&xdT[i1*32 + g8*4];
      ax += v1.x; ay += v1.y; az += v1.z; aw += v1.w;
    }
    #pragma unroll
    for (int m=8; m<=32; m<<=1){
      ax += __shfl_xor(ax, m, 64); ay += __shfl_xor(ay, m, 64);
      az += __shfl_xor(az, m, 64); aw += __shfl_xor(aw, m, 64);
    }
    if (s8 == 0){
      float4 sv = *(const float4*)&xdT[n*32 + g8*4];
      float dn = dinv[n];
      float4 o;
      o.x = dn*(ax + sv.x); o.y = dn*(ay + sv.y);
      o.z = dn*(az + sv.z); o.w = dn*(aw + sv.w);
      *(float4*)&P[n*32 + g8*4] = o;
    }
  }
}

// ---------------- k_hw2: hw2d[flat][lane] = bf16( dinv[n] * relu(p*W1+b1) @ W2 ), flat=(t*2+b)*N+n ----------------
__global__ void __launch_bounds__(256) k_hw2(
    const float* __restrict__ P, const float* __restrict__ dinv,
    const float* __restrict__ W1, const float* __restrict__ b1,
    const float* __restrict__ W2, unsigned short* __restrict__ hw2d)
{
  __shared__ float sW2[4096];
  __shared__ float sW1[64], sb1[64];
  int tid = threadIdx.x;
  for (int i = tid; i < 4096; i += 256) sW2[i] = W2[i];
  if (tid < 64) { sW1[tid] = W1[tid]; sb1[tid] = b1[tid]; }
  __syncthreads();
  int wv = tid >> 6, lane = tid & 63;
  float p[4], dn[4];
  int fl[4];
  #pragma unroll
  for (int i=0;i<4;i++){
    int flat = blockIdx.x*RB + wv*4 + i;      // 0..119999
    int sl = flat / N_NODES;                   // t*2+b
    int n  = flat - sl*N_NODES;
    int b  = sl & 1, t = sl >> 1;
    p[i]  = P[n*32 + b*12 + t];
    dn[i] = dinv[n];
    fl[i] = flat;
  }
  float a[4] = {0.f,0.f,0.f,0.f};
  #pragma unroll 8
  for (int k=0;k<64;k++){
    float w2 = sW2[k*64 + lane];
    float w1 = sW1[k], bk = sb1[k];
    #pragma unroll
    for (int i=0;i<4;i++)
      a[i] = fmaf(fmaxf(fmaf(p[i], w1, bk), 0.f), w2, a[i]);
  }
  #pragma unroll
  for (int i=0;i<4;i++)
    hw2d[(size_t)fl[i]*64 + lane] = f2bf(dn[i]*a[i]);
}

// ---------------- k_agg: agg2[t][r][64] = D^-1/2 (A+I) hw2d, 2 timesteps per block ----------------
__global__ void __launch_bounds__(256) k_agg(
    const unsigned short* __restrict__ hw2d,   // [t][b][n][64] bf16
    const int* __restrict__ row_ptr, const int* __restrict__ csr_src,
    const float* __restrict__ dinv, float* __restrict__ agg2)
{
  int tid = threadIdx.x;
  int wk = swz3750(blockIdx.x);
  int tg = wk / NRB;            // 0..5 -> timesteps 2tg, 2tg+1
  int rb = wk % NRB;
  int r0 = rb*RB;
  int wv = tid >> 6, lane = tid & 63;
  int s8 = lane >> 3, g8 = lane & 7;   // 8 edge-slots x 8 col-groups (ushort8)
  #pragma unroll
  for (int i=0;i<4;i++){
    int r = r0 + wv*4 + i;
    int b = (r >= N_NODES) ? 1 : 0;
    int n = r - b*N_NODES;
    const unsigned short* h0 = hw2d + ((size_t)(2*tg)*BATCH + b)*N_NODES*64;
    const unsigned short* h1 = h0 + (size_t)BATCH*N_NODES*64;
    int e0 = row_ptr[n], e1 = row_ptr[n+1];
    float a0[8] = {0,0,0,0,0,0,0,0};
    float a1[8] = {0,0,0,0,0,0,0,0};
    int e = e0 + s8;
    for (; e + 8 < e1; e += 16){
      size_t oA = (size_t)csr_src[e]*64 + g8*8;
      size_t oB = (size_t)csr_src[e+8]*64 + g8*8;
      ushort8_t uA0 = *(const ushort8_t*)(h0 + oA);
      ushort8_t uA1 = *(const ushort8_t*)(h1 + oA);
      ushort8_t uB0 = *(const ushort8_t*)(h0 + oB);
      ushort8_t uB1 = *(const ushort8_t*)(h1 + oB);
      #pragma unroll
      for (int j=0;j<8;j++){
        a0[j] += bf2f(uA0[j]) + bf2f(uB0[j]);
        a1[j] += bf2f(uA1[j]) + bf2f(uB1[j]);
      }
    }
    if (e < e1){
      size_t oA = (size_t)csr_src[e]*64 + g8*8;
      ushort8_t uA0 = *(const ushort8_t*)(h0 + oA);
      ushort8_t uA1 = *(const ushort8_t*)(h1 + oA);
      #pragma unroll
      for (int j=0;j<8;j++){ a0[j] += bf2f(uA0[j]); a1[j] += bf2f(uA1[j]); }
    }
    #pragma unroll
    for (int m=8; m<=32; m<<=1){
      #pragma unroll
      for (int j=0;j<8;j++){
        a0[j] += __shfl_xor(a0[j], m, 64);
        a1[j] += __shfl_xor(a1[j], m, 64);
      }
    }
    if (s8 == 0){
      size_t so = (size_t)n*64 + g8*8;
      ushort8_t sv0 = *(const ushort8_t*)(h0 + so);
      ushort8_t sv1 = *(const ushort8_t*)(h1 + so);
      float dn = dinv[n];
      float4 o00, o01, o10, o11;
      o00.x = dn*(a0[0]+bf2f(sv0[0])); o00.y = dn*(a0[1]+bf2f(sv0[1]));
      o00.z = dn*(a0[2]+bf2f(sv0[2])); o00.w = dn*(a0[3]+bf2f(sv0[3]));
      o01.x = dn*(a0[4]+bf2f(sv0[4])); o01.y = dn*(a0[5]+bf2f(sv0[5]));
      o01.z = dn*(a0[6]+bf2f(sv0[6])); o01.w = dn*(a0[7]+bf2f(sv0[7]));
      o10.x = dn*(a1[0]+bf2f(sv1[0])); o10.y = dn*(a1[1]+bf2f(sv1[1]));
      o10.z = dn*(a1[2]+bf2f(sv1[2])); o10.w = dn*(a1[3]+bf2f(sv1[3]));
      o11.x = dn*(a1[4]+bf2f(sv1[4])); o11.y = dn*(a1[5]+bf2f(sv1[5]));
      o11.z = dn*(a1[6]+bf2f(sv1[6])); o11.w = dn*(a1[7]+bf2f(sv1[7]));
      float* d0 = &agg2[((size_t)(2*tg)*ROWS + r)*64 + g8*8];
      float* d1 = &agg2[((size_t)(2*tg+1)*ROWS + r)*64 + g8*8];
      *(float4*)d0 = o00; *(float4*)(d0+4) = o01;
      *(float4*)d1 = o10; *(float4*)(d1+4) = o11;
    }
  }
}

// ---------------- k_lstm: persistent 12-step LSTM, K=128 MFMA [agg | h] (round-4 verified) ----------------
__global__ void __launch_bounds__(256) k_lstm(
    const float* __restrict__ agg2,
    const unsigned short* __restrict__ WF,   // 4 kt-tiles: 0,1=W_ih  2,3=W_hh
    const float* __restrict__ biasT,
    const float* __restrict__ fc_w, const float* __restrict__ fc_b,
    float* __restrict__ out)
{
  __shared__ unsigned short sHh[RB*72];   // h hi, bf16, row stride 72
  __shared__ unsigned short sHl[RB*72];   // h lo
  __shared__ float sG[RB*260];            // gates [16][256+4]
  int tid = threadIdx.x;
  int r0 = blockIdx.x*RB;
  int wv = tid >> 6, lane = tid & 63;
  int row = lane & 15, kg = lane >> 4;
  int urow = tid >> 4, uc0 = (tid & 15)*4;   // update mapping: 16 rows x 16 col-quads

  float creg[4] = {0.f,0.f,0.f,0.f};
  float hn[4]   = {0.f,0.f,0.f,0.f};

  // prefetch agg A-tile for t=0: lane (row,kg) loads 8 f32 per kt (coalesced 4KB/wave)
  float4 p00,p01,p10,p11;
  {
    const float* base = &agg2[((size_t)(r0 + row))*64 + kg*8];
    p00 = *(const float4*)base;      p01 = *(const float4*)(base+4);
    p10 = *(const float4*)(base+32); p11 = *(const float4*)(base+36);
  }

  for (int t=0; t<TSTEPS; ++t){
    // convert current agg prefetch to split-bf16 A-fragments (kt 0,1)
    short8_t Ah[2], Al[2];
    {
      float xs0[8] = {p00.x,p00.y,p00.z,p00.w,p01.x,p01.y,p01.z,p01.w};
      float xs1[8] = {p10.x,p10.y,p10.z,p10.w,p11.x,p11.y,p11.z,p11.w};
      #pragma unroll
      for (int j=0;j<8;j++){
        unsigned short h0 = f2bf(xs0[j]);
        Ah[0][j] = (short)h0; Al[0][j] = (short)f2bf(xs0[j] - bf2f(h0));
        unsigned short h1 = f2bf(xs1[j]);
        Ah[1][j] = (short)h1; Al[1][j] = (short)f2bf(xs1[j] - bf2f(h1));
      }
    }
    // issue next-t prefetch
    if (t+1 < TSTEPS){
      const float* base = &agg2[((size_t)(t+1)*ROWS + r0 + row)*64 + kg*8];
      p00 = *(const float4*)base;      p01 = *(const float4*)(base+4);
      p10 = *(const float4*)(base+32); p11 = *(const float4*)(base+36);
    }
    // h A-fragments from LDS (kt 2,3), valid for t>0
    short8_t Hh[2], Hl[2];
    if (t > 0){
      #pragma unroll
      for (int kt=0; kt<2; kt++){
        int hoff = row*72 + kt*32 + kg*8;
        Hh[kt] = *(const short8_t*)&sHh[hoff];
        Hl[kt] = *(const short8_t*)&sHl[hoff];
      }
    }
    f32x4 acc[4];
    #pragma unroll
    for (int i=0;i<4;i++){
      float bs = biasT[(wv*4+i)*16 + row];
      acc[i][0]=bs; acc[i][1]=bs; acc[i][2]=bs; acc[i][3]=bs;
    }
    #pragma unroll
    for (int i=0;i<4;i++){
      int ct = wv*4 + i;
      f32x4 a = acc[i];
      #pragma unroll
      for (int kt=0; kt<2; kt++){
        size_t base = ((size_t)(kt*16 + ct))*1024 + (size_t)lane*8;
        short8_t bh = *(const short8_t*)(WF + base);
        short8_t bl = *(const short8_t*)(WF + base + 512);
        a = __builtin_amdgcn_mfma_f32_16x16x32_bf16(Ah[kt], bh, a, 0, 0, 0);
        a = __builtin_amdgcn_mfma_f32_16x16x32_bf16(Ah[kt], bl, a, 0, 0, 0);
        a = __builtin_amdgcn_mfma_f32_16x16x32_bf16(Al[kt], bh, a, 0, 0, 0);
      }
      if (t > 0){
        #pragma unroll
        for (int kt=0; kt<2; kt++){
          size_t base = ((size_t)((2+kt)*16 + ct))*1024 + (size_t)lane*8;
          short8_t bh = *(const short8_t*)(WF + base);
          short8_t bl = *(const short8_t*)(WF + base + 512);
          a = __builtin_amdgcn_mfma_f32_16x16x32_bf16(Hh[kt], bh, a, 0, 0, 0);
          a = __builtin_amdgcn_mfma_f32_16x16x32_bf16(Hh[kt], bl, a, 0, 0, 0);
          a = __builtin_amdgcn_mfma_f32_16x16x32_bf16(Hl[kt], bh, a, 0, 0, 0);
        }
      }
      acc[i] = a;
    }
    // stash gates to LDS   (D layout: col = lane&15, row = (lane>>4)*4 + reg)
    #pragma unroll
    for (int i=0;i<4;i++){
      int col = (wv*4+i)*16 + row;
      #pragma unroll
      for (int rr=0;rr<4;rr++)
        sG[(kg*4+rr)*260 + col] = acc[i][rr];
    }
    __syncthreads();
    // LSTM update
    {
      float4 gi = *(const float4*)&sG[urow*260 + uc0];
      float4 gf = *(const float4*)&sG[urow*260 + 64  + uc0];
      float4 gg = *(const float4*)&sG[urow*260 + 128 + uc0];
      float4 go = *(const float4*)&sG[urow*260 + 192 + uc0];
      float gis[4] = {gi.x,gi.y,gi.z,gi.w};
      float gfs[4] = {gf.x,gf.y,gf.z,gf.w};
      float ggs[4] = {gg.x,gg.y,gg.z,gg.w};
      float gos[4] = {go.x,go.y,go.z,go.w};
      unsigned short hh[4], hl[4];
      #pragma unroll
      for (int j=0;j<4;j++){
        float si = 1.f/(1.f + __expf(-gis[j]));
        float sf = 1.f/(1.f + __expf(-gfs[j]));
        float so = 1.f/(1.f + __expf(-gos[j]));
        float tg = tanhf(ggs[j]);
        float cn = sf*creg[j] + si*tg;
        creg[j] = cn;
        hn[j] = so*tanhf(cn);
        hh[j] = f2bf(hn[j]);
        hl[j] = f2bf(hn[j] - bf2f(hh[j]));
      }
      unsigned w0 = (unsigned)hh[0] | ((unsigned)hh[1] << 16);
      unsigned w1 = (unsigned)hh[2] | ((unsigned)hh[3] << 16);
      unsigned v0 = (unsigned)hl[0] | ((unsigned)hl[1] << 16);
      unsigned v1 = (unsigned)hl[2] | ((unsigned)hl[3] << 16);
      *(uint2*)&sHh[urow*72 + uc0] = make_uint2(w0, w1);
      *(uint2*)&sHl[urow*72 + uc0] = make_uint2(v0, v1);
    }
    __syncthreads();
  }
  // final projection: out[r] = sum_j h[r][j]*fc_w[j] + fc_b
  float4 fw = *(const float4*)&fc_w[uc0];
  float v = hn[0]*fw.x + hn[1]*fw.y + hn[2]*fw.z + hn[3]*fw.w;
  v += __shfl_xor(v, 1, 64);
  v += __shfl_xor(v, 2, 64);
  v += __shfl_xor(v, 4, 64);
  v += __shfl_xor(v, 8, 64);
  if ((lane & 15) == 0) out[r0 + urow] = v + fc_b[0];
}

extern "C" void kernel_launch(void* const* d_in, const int* in_sizes, int n_in,
                              void* d_out, int out_size, void* d_ws, size_t ws_size,
                              hipStream_t stream) {
  const float* x    = (const float*)d_in[0];
  const int*   ei   = (const int*)d_in[1];
  const float* W1   = (const float*)d_in[2];
  const float* b1   = (const float*)d_in[3];
  const float* W2   = (const float*)d_in[4];
  const float* b2   = (const float*)d_in[5];
  const float* W_ih = (const float*)d_in[6];
  const float* W_hh = (const float*)d_in[7];
  const float* b_ih = (const float*)d_in[8];
  const float* b_hh = (const float*)d_in[9];
  const float* fc_w = (const float*)d_in[10];
  const float* fc_b = (const float*)d_in[11];
  float* out = (float*)d_out;

  char* ws = (char*)d_ws;
  size_t off = 0;
  auto alloc = [&](size_t bytes)->void* { void* p = ws + off; off += (bytes + 255) & ~255ul; return p; };
  float*          dinv    = (float*)alloc(N_NODES*4);
  int*            cntfill = (int*)alloc(2*N_NODES*4);      // [0:N)=cnt, [N:2N)=fill
  int*            row_ptr = (int*)alloc((N_NODES+1)*4);
  int*            csr_src = (int*)alloc(N_EDGES*4);
  unsigned short* WF      = (unsigned short*)alloc(2*2*16*1024*2);  // 128 KB
  float*          biasT   = (float*)alloc(256*4);
  float*          xdT     = (float*)alloc((size_t)N_NODES*32*4);    // 640 KB
  float*          P       = (float*)alloc((size_t)N_NODES*32*4);    // 640 KB
  unsigned short* hw2d    = (unsigned short*)alloc((size_t)TSTEPS*BATCH*N_NODES*64*2); // 15.4 MB
  float*          agg2    = (float*)alloc((size_t)TSTEPS*ROWS*64*4);                   // 30.7 MB

  int* cnt  = cntfill;
  int* fill = cntfill + N_NODES;

  hipMemsetAsync(cntfill, 0, 2*N_NODES*4, stream);

  k1    <<<642, 256, 0, stream>>>(ei, cnt, W_ih, W_hh, b_ih, b_hh, b2, WF, biasT);
  k_scan<<<1, 1024, 0, stream>>>(cnt, row_ptr, dinv);
  k2    <<<1250, 256, 0, stream>>>(ei, row_ptr, fill, csr_src, x, dinv, xdT);
  k_p   <<<(N_NODES+RB-1)/RB, 256, 0, stream>>>(xdT, row_ptr, csr_src, dinv, P);
  k_hw2 <<<TSTEPS*BATCH*N_NODES/RB, 256, 0, stream>>>(P, dinv, W1, b1, W2, hw2d);
  k_agg <<<(TSTEPS/2)*NRB, 256, 0, stream>>>(hw2d, row_ptr, csr_src, dinv, agg2);
  k_lstm<<<NRB, 256, 0, stream>>>(agg2, WF, biasT, fc_w, fc_b, out);
}

// Round 7
// 173.108 us; speedup vs baseline: 2.1032x; 1.0575x over previous
//
#include <hip/hip_runtime.h>

#define N_NODES 5000
#define N_EDGES 160000
#define BATCH 2
#define TSTEPS 12
#define ROWS (BATCH*N_NODES)   // 10000
#define RB 16                  // rows per block
#define NRB (ROWS/RB)          // 625

typedef _Float16 half8_t __attribute__((ext_vector_type(8)));
typedef float f32x4 __attribute__((ext_vector_type(4)));

__device__ inline unsigned short f2bf(float f){
  union { float f; unsigned u; } v; v.f = f;
  unsigned r = v.u + 0x7fff + ((v.u >> 16) & 1);   // RNE
  return (unsigned short)(r >> 16);
}

// Bijective XCD swizzle for grid 2500 = 4*313 + 4*312 (gid = i*8 + xcd)
__device__ inline int swz2500(int gid){
  int xcd = gid & 7, i = gid >> 3;
  return (xcd < 4 ? xcd*313 + i : 4*313 + (xcd-4)*312 + i);
}

// ---------------- k1: edge-degree count (blocks 0..624) + WF f16 fragments (625..640) + permuted bias (641) ----------------
// WF[(kt4*16+ct)*512 + lane*8 + j] = (f16) W[colP][kt*32+(lane>>4)*8+j]
//   colP = (ct&3)*64 + (ct>>2)*16 + (lane&15)   (gate-interleave permutation)
//   kt4: 0,1 = W_ih (K 0..63), 2,3 = W_hh (K 64..127)
__global__ void k1(const int* __restrict__ ei, int* __restrict__ cnt,
                   const float* __restrict__ W_ih, const float* __restrict__ W_hh,
                   const float* __restrict__ b_ih, const float* __restrict__ b_hh,
                   const float* __restrict__ b2,
                   _Float16* __restrict__ WF, float* __restrict__ biasP) {
  int bid = blockIdx.x;
  if (bid < 625) {
    int e = bid*256 + threadIdx.x;
    if (e < N_EDGES) atomicAdd(&cnt[ei[N_EDGES + e]], 1);
    return;
  }
  bid -= 625;
  if (bid == 16) {
    int j = threadIdx.x;                    // permuted index
    int ct = j >> 4, c16 = j & 15;
    int o = (ct&3)*64 + (ct>>2)*16 + c16;   // original gate column
    float s = b_ih[o] + b_hh[o];
    for (int k=0;k<64;k++) s = fmaf(b2[k], W_ih[o*64+k], s);
    biasP[j] = s;
    return;
  }
  int idx = bid*256 + threadIdx.x;    // 0..4095
  int lane = idx & 63;
  int ct   = (idx >> 6) & 15;
  int kt4  = idx >> 10;               // 0..3
  const float* W = (kt4 >= 2) ? W_hh : W_ih;
  int kt  = kt4 & 1;
  int col = (ct&3)*64 + (ct>>2)*16 + (lane & 15);
  int k0  = kt*32 + (lane >> 4)*8;
  size_t base = ((size_t)(kt4*16 + ct))*512 + (size_t)lane*8;
  #pragma unroll
  for (int j=0;j<8;j++) WF[base + j] = (_Float16)W[col*64 + k0 + j];
}

__global__ void k_scan(const int* __restrict__ cnt, int* __restrict__ row_ptr,
                       float* __restrict__ dinv) {
  __shared__ int sums[1024];
  int tid = threadIdx.x;
  constexpr int C = (N_NODES + 1023)/1024; // 5
  int base = tid*C;
  int local[C];
  int s = 0;
  #pragma unroll
  for (int i=0;i<C;i++){ int idx=base+i; int v=(idx<N_NODES)?cnt[idx]:0; local[i]=s; s+=v; }
  sums[tid]=s; __syncthreads();
  for (int off=1; off<1024; off<<=1) {
    int v = sums[tid];
    int add = (tid>=off)? sums[tid-off]:0;
    __syncthreads();
    sums[tid] = v + add;
    __syncthreads();
  }
  int excl = (tid>0)? sums[tid-1]:0;
  #pragma unroll
  for (int i=0;i<C;i++){ int idx=base+i; if(idx<N_NODES) row_ptr[idx]=excl+local[i]; }
  if (tid==0) row_ptr[N_NODES] = sums[1023];
  #pragma unroll
  for (int i=0;i<C;i++){ int idx=base+i; if(idx<N_NODES) dinv[idx]=rsqrtf((float)(cnt[idx]+1)); }
}

// ---------------- k2: CSR fill (blocks 0..624) + xdT build (625..1249) ----------------
__global__ void k2(const int* __restrict__ ei, const int* __restrict__ row_ptr,
                   int* __restrict__ fill, int* __restrict__ csr_src,
                   const float* __restrict__ x, const float* __restrict__ dinv,
                   float* __restrict__ xdT) {
  int bid = blockIdx.x;
  if (bid < 625) {
    int e = bid*256 + threadIdx.x;
    if (e < N_EDGES) {
      int src = ei[e], dst = ei[N_EDGES+e];
      int pos = row_ptr[dst] + atomicAdd(&fill[dst],1);
      csr_src[pos] = src;
    }
    return;
  }
  int i = (bid-625)*256 + threadIdx.x;   // 0..159999 = 5000*32
  int n = i >> 5, c = i & 31;
  xdT[i] = (c < 24) ? x[c*N_NODES + n] * dinv[n] : 0.f;
}

// ---------------- k_p: P[n][tb] = dinv[n]*(sum_src xdT[src][tb] + xdT[n][tb]) ----------------
__global__ void __launch_bounds__(256) k_p(
    const float* __restrict__ xdT,
    const int* __restrict__ row_ptr, const int* __restrict__ csr_src,
    const float* __restrict__ dinv, float* __restrict__ P)
{
  int tid = threadIdx.x;
  int wv = tid >> 6, lane = tid & 63;
  int s8 = lane >> 3, g8 = lane & 7;
  #pragma unroll
  for (int i=0;i<4;i++){
    int n = blockIdx.x*RB + wv*4 + i;
    if (n >= N_NODES) continue;
    int e0 = row_ptr[n], e1 = row_ptr[n+1];
    float ax=0.f, ay=0.f, az=0.f, aw=0.f;
    int e = e0 + s8;
    for (; e + 8 < e1; e += 16){
      int i1 = csr_src[e], i2 = csr_src[e+8];
      float4 v1 = *(const float4*)&xdT[i1*32 + g8*4];
      float4 v2 = *(const float4*)&xdT[i2*32 + g8*4];
      ax += v1.x + v2.x; ay += v1.y + v2.y;
      az += v1.z + v2.z; aw += v1.w + v2.w;
    }
    if (e < e1){
      int i1 = csr_src[e];
      float4 v1 = *(const float4*)&xdT[i1*32 + g8*4];
      ax += v1.x; ay += v1.y; az += v1.z; aw += v1.w;
    }
    #pragma unroll
    for (int m=8; m<=32; m<<=1){
      ax += __shfl_xor(ax, m, 64); ay += __shfl_xor(ay, m, 64);
      az += __shfl_xor(az, m, 64); aw += __shfl_xor(aw, m, 64);
    }
    if (s8 == 0){
      float4 sv = *(const float4*)&xdT[n*32 + g8*4];
      float dn = dinv[n];
      float4 o;
      o.x = dn*(ax + sv.x); o.y = dn*(ay + sv.y);
      o.z = dn*(az + sv.z); o.w = dn*(aw + sv.w);
      *(float4*)&P[n*32 + g8*4] = o;
    }
  }
}

// ---------------- k_hw2: hw2d[flat][lane] = f16( dinv[n] * relu(p*W1+b1) @ W2 ), flat=(t*2+b)*N+n ----------------
__global__ void __launch_bounds__(256) k_hw2(
    const float* __restrict__ P, const float* __restrict__ dinv,
    const float* __restrict__ W1, const float* __restrict__ b1,
    const float* __restrict__ W2, _Float16* __restrict__ hw2d)
{
  __shared__ float sW2[4096];
  __shared__ float sW1[64], sb1[64];
  int tid = threadIdx.x;
  for (int i = tid; i < 4096; i += 256) sW2[i] = W2[i];
  if (tid < 64) { sW1[tid] = W1[tid]; sb1[tid] = b1[tid]; }
  __syncthreads();
  int wv = tid >> 6, lane = tid & 63;
  float p[4], dn[4];
  int fl[4];
  #pragma unroll
  for (int i=0;i<4;i++){
    int flat = blockIdx.x*RB + wv*4 + i;      // 0..119999
    int sl = flat / N_NODES;                   // t*2+b
    int n  = flat - sl*N_NODES;
    int b  = sl & 1, t = sl >> 1;
    p[i]  = P[n*32 + b*12 + t];
    dn[i] = dinv[n];
    fl[i] = flat;
  }
  float a[4] = {0.f,0.f,0.f,0.f};
  #pragma unroll 8
  for (int k=0;k<64;k++){
    float w2 = sW2[k*64 + lane];
    float w1 = sW1[k], bk = sb1[k];
    #pragma unroll
    for (int i=0;i<4;i++)
      a[i] = fmaf(fmaxf(fmaf(p[i], w1, bk), 0.f), w2, a[i]);
  }
  #pragma unroll
  for (int i=0;i<4;i++)
    hw2d[(size_t)fl[i]*64 + lane] = (_Float16)(dn[i]*a[i]);
}

// ---------------- k_agg: agg2[t][r][64] = D^-1/2 (A+I) hw2d, 3 timesteps per block ----------------
__global__ void __launch_bounds__(256) k_agg(
    const _Float16* __restrict__ hw2d,   // [t][b][n][64] f16
    const int* __restrict__ row_ptr, const int* __restrict__ csr_src,
    const float* __restrict__ dinv, float* __restrict__ agg2)
{
  int tid = threadIdx.x;
  int wk = swz2500(blockIdx.x);
  int tg = wk / NRB;            // 0..3 -> timesteps 3tg..3tg+2
  int rb = wk % NRB;
  int r0 = rb*RB;
  int wv = tid >> 6, lane = tid & 63;
  int s8 = lane >> 3, g8 = lane & 7;   // 8 edge-slots x 8 col-groups (half8)
  #pragma unroll
  for (int i=0;i<4;i++){
    int r = r0 + wv*4 + i;
    int b = (r >= N_NODES) ? 1 : 0;
    int n = r - b*N_NODES;
    const _Float16* h0 = hw2d + ((size_t)(3*tg)*BATCH + b)*N_NODES*64;
    const _Float16* h1 = h0 + (size_t)BATCH*N_NODES*64;
    const _Float16* h2 = h1 + (size_t)BATCH*N_NODES*64;
    int e0 = row_ptr[n], e1 = row_ptr[n+1];
    float a0[8] = {0,0,0,0,0,0,0,0};
    float a1[8] = {0,0,0,0,0,0,0,0};
    float a2[8] = {0,0,0,0,0,0,0,0};
    int e = e0 + s8;
    for (; e + 8 < e1; e += 16){
      size_t oA = (size_t)csr_src[e]*64 + g8*8;
      size_t oB = (size_t)csr_src[e+8]*64 + g8*8;
      half8_t uA0 = *(const half8_t*)(h0 + oA);
      half8_t uA1 = *(const half8_t*)(h1 + oA);
      half8_t uA2 = *(const half8_t*)(h2 + oA);
      half8_t uB0 = *(const half8_t*)(h0 + oB);
      half8_t uB1 = *(const half8_t*)(h1 + oB);
      half8_t uB2 = *(const half8_t*)(h2 + oB);
      #pragma unroll
      for (int j=0;j<8;j++){
        a0[j] += (float)uA0[j] + (float)uB0[j];
        a1[j] += (float)uA1[j] + (float)uB1[j];
        a2[j] += (float)uA2[j] + (float)uB2[j];
      }
    }
    if (e < e1){
      size_t oA = (size_t)csr_src[e]*64 + g8*8;
      half8_t uA0 = *(const half8_t*)(h0 + oA);
      half8_t uA1 = *(const half8_t*)(h1 + oA);
      half8_t uA2 = *(const half8_t*)(h2 + oA);
      #pragma unroll
      for (int j=0;j<8;j++){
        a0[j] += (float)uA0[j]; a1[j] += (float)uA1[j]; a2[j] += (float)uA2[j];
      }
    }
    #pragma unroll
    for (int m=8; m<=32; m<<=1){
      #pragma unroll
      for (int j=0;j<8;j++){
        a0[j] += __shfl_xor(a0[j], m, 64);
        a1[j] += __shfl_xor(a1[j], m, 64);
        a2[j] += __shfl_xor(a2[j], m, 64);
      }
    }
    if (s8 == 0){
      size_t so = (size_t)n*64 + g8*8;
      half8_t sv0 = *(const half8_t*)(h0 + so);
      half8_t sv1 = *(const half8_t*)(h1 + so);
      half8_t sv2 = *(const half8_t*)(h2 + so);
      float dn = dinv[n];
      float o0[8], o1[8], o2[8];
      #pragma unroll
      for (int j=0;j<8;j++){
        o0[j] = dn*(a0[j] + (float)sv0[j]);
        o1[j] = dn*(a1[j] + (float)sv1[j]);
        o2[j] = dn*(a2[j] + (float)sv2[j]);
      }
      float* d0 = &agg2[((size_t)(3*tg)*ROWS + r)*64 + g8*8];
      float* d1 = d0 + (size_t)ROWS*64;
      float* d2 = d1 + (size_t)ROWS*64;
      *(float4*)d0 = make_float4(o0[0],o0[1],o0[2],o0[3]);
      *(float4*)(d0+4) = make_float4(o0[4],o0[5],o0[6],o0[7]);
      *(float4*)d1 = make_float4(o1[0],o1[1],o1[2],o1[3]);
      *(float4*)(d1+4) = make_float4(o1[4],o1[5],o1[6],o1[7]);
      *(float4*)d2 = make_float4(o2[0],o2[1],o2[2],o2[3]);
      *(float4*)(d2+4) = make_float4(o2[4],o2[5],o2[6],o2[7]);
    }
  }
}

// ---------------- k_lstm: persistent 12-step LSTM, f16 MFMA, weights in VGPRs, in-register gates ----------------
__global__ void __launch_bounds__(256) k_lstm(
    const float* __restrict__ agg2,
    const _Float16* __restrict__ WF,   // 4 kt4-tiles x 16 ct, permuted cols, f16
    const float* __restrict__ biasP,
    const float* __restrict__ fc_w, const float* __restrict__ fc_b,
    float* __restrict__ out)
{
  __shared__ _Float16 sH[2][RB][72];   // h, f16, double-buffered
  __shared__ float sRed[4][16];
  int tid = threadIdx.x;
  int r0 = blockIdx.x*RB;
  int wv = tid >> 6, lane = tid & 63;
  int row = lane & 15, kg = lane >> 4;
  int j = wv*16 + row;                 // this thread's h-column (gate-permuted layout)

  // weights: all 16 (kt4, ct=wv*4+i) tiles into registers, once
  half8_t Wr[4][4];
  #pragma unroll
  for (int kt4=0; kt4<4; ++kt4)
    #pragma unroll
    for (int i=0;i<4;i++)
      Wr[kt4][i] = *(const half8_t*)(WF + ((size_t)(kt4*16 + wv*4 + i))*512 + (size_t)lane*8);

  float bias[4];
  #pragma unroll
  for (int i=0;i<4;i++) bias[i] = biasP[(wv*4+i)*16 + row];

  float creg[4] = {0.f,0.f,0.f,0.f};
  float hn[4]   = {0.f,0.f,0.f,0.f};

  // prefetch agg A-tile for t=0
  float4 p00,p01,p10,p11;
  {
    const float* base = &agg2[((size_t)(r0 + row))*64 + kg*8];
    p00 = *(const float4*)base;      p01 = *(const float4*)(base+4);
    p10 = *(const float4*)(base+32); p11 = *(const float4*)(base+36);
  }

  int pb = 0;
  for (int t=0; t<TSTEPS; ++t){
    // A-fragments (agg, K 0..63) from prefetch, f16 single
    half8_t Af[2];
    {
      float xs0[8] = {p00.x,p00.y,p00.z,p00.w,p01.x,p01.y,p01.z,p01.w};
      float xs1[8] = {p10.x,p10.y,p10.z,p10.w,p11.x,p11.y,p11.z,p11.w};
      #pragma unroll
      for (int q=0;q<8;q++){ Af[0][q] = (_Float16)xs0[q]; Af[1][q] = (_Float16)xs1[q]; }
    }
    if (t+1 < TSTEPS){
      const float* base = &agg2[((size_t)(t+1)*ROWS + r0 + row)*64 + kg*8];
      p00 = *(const float4*)base;      p01 = *(const float4*)(base+4);
      p10 = *(const float4*)(base+32); p11 = *(const float4*)(base+36);
    }
    // H-fragments (K 64..127) from LDS
    half8_t Hf[2];
    if (t > 0){
      Hf[0] = *(const half8_t*)&sH[pb][row][kg*8];
      Hf[1] = *(const half8_t*)&sH[pb][row][32 + kg*8];
    }
    f32x4 acc[4];
    #pragma unroll
    for (int i=0;i<4;i++){ acc[i][0]=bias[i]; acc[i][1]=bias[i]; acc[i][2]=bias[i]; acc[i][3]=bias[i]; }
    #pragma unroll
    for (int i=0;i<4;i++){
      f32x4 a = acc[i];
      a = __builtin_amdgcn_mfma_f32_16x16x32_f16(Af[0], Wr[0][i], a, 0, 0, 0);
      a = __builtin_amdgcn_mfma_f32_16x16x32_f16(Af[1], Wr[1][i], a, 0, 0, 0);
      if (t > 0){
        a = __builtin_amdgcn_mfma_f32_16x16x32_f16(Hf[0], Wr[2][i], a, 0, 0, 0);
        a = __builtin_amdgcn_mfma_f32_16x16x32_f16(Hf[1], Wr[3][i], a, 0, 0, 0);
      }
      acc[i] = a;
    }
    // in-register LSTM update: acc[i][rr] = gate_i for row kg*4+rr, col j
    #pragma unroll
    for (int rr=0;rr<4;rr++){
      float gi = acc[0][rr], gf = acc[1][rr], gg = acc[2][rr], go = acc[3][rr];
      float si = 1.f/(1.f + __expf(-gi));
      float sf = 1.f/(1.f + __expf(-gf));
      float so = 1.f/(1.f + __expf(-go));
      float tg = 2.f/(1.f + __expf(-2.f*gg)) - 1.f;
      float cn = sf*creg[rr] + si*tg;
      creg[rr] = cn;
      float tc = 2.f/(1.f + __expf(-2.f*cn)) - 1.f;
      hn[rr] = so*tc;
      sH[pb^1][kg*4+rr][j] = (_Float16)hn[rr];
    }
    __syncthreads();
    pb ^= 1;
  }
  // final projection: out[r] = sum_j h[r][j]*fc_w[j] + fc_b
  float fw = fc_w[j];
  #pragma unroll
  for (int rr=0;rr<4;rr++){
    float pv = hn[rr]*fw;
    pv += __shfl_xor(pv, 1, 64);
    pv += __shfl_xor(pv, 2, 64);
    pv += __shfl_xor(pv, 4, 64);
    pv += __shfl_xor(pv, 8, 64);
    if (row == 0) sRed[wv][kg*4+rr] = pv;
  }
  __syncthreads();
  if (tid < 16)
    out[r0 + tid] = sRed[0][tid] + sRed[1][tid] + sRed[2][tid] + sRed[3][tid] + fc_b[0];
}

extern "C" void kernel_launch(void* const* d_in, const int* in_sizes, int n_in,
                              void* d_out, int out_size, void* d_ws, size_t ws_size,
                              hipStream_t stream) {
  const float* x    = (const float*)d_in[0];
  const int*   ei   = (const int*)d_in[1];
  const float* W1   = (const float*)d_in[2];
  const float* b1   = (const float*)d_in[3];
  const float* W2   = (const float*)d_in[4];
  const float* b2   = (const float*)d_in[5];
  const float* W_ih = (const float*)d_in[6];
  const float* W_hh = (const float*)d_in[7];
  const float* b_ih = (const float*)d_in[8];
  const float* b_hh = (const float*)d_in[9];
  const float* fc_w = (const float*)d_in[10];
  const float* fc_b = (const float*)d_in[11];
  float* out = (float*)d_out;

  char* ws = (char*)d_ws;
  size_t off = 0;
  auto alloc = [&](size_t bytes)->void* { void* p = ws + off; off += (bytes + 255) & ~255ul; return p; };
  float*     dinv    = (float*)alloc(N_NODES*4);
  int*       cntfill = (int*)alloc(2*N_NODES*4);      // [0:N)=cnt, [N:2N)=fill
  int*       row_ptr = (int*)alloc((N_NODES+1)*4);
  int*       csr_src = (int*)alloc(N_EDGES*4);
  _Float16*  WF      = (_Float16*)alloc(4*16*512*2);  // 64 KB, f16 fragments
  float*     biasP   = (float*)alloc(256*4);
  float*     xdT     = (float*)alloc((size_t)N_NODES*32*4);    // 640 KB
  float*     P       = (float*)alloc((size_t)N_NODES*32*4);    // 640 KB
  _Float16*  hw2d    = (_Float16*)alloc((size_t)TSTEPS*BATCH*N_NODES*64*2); // 15.4 MB
  float*     agg2    = (float*)alloc((size_t)TSTEPS*ROWS*64*4);             // 30.7 MB

  int* cnt  = cntfill;
  int* fill = cntfill + N_NODES;

  hipMemsetAsync(cntfill, 0, 2*N_NODES*4, stream);

  k1    <<<642, 256, 0, stream>>>(ei, cnt, W_ih, W_hh, b_ih, b_hh, b2, WF, biasP);
  k_scan<<<1, 1024, 0, stream>>>(cnt, row_ptr, dinv);
  k2    <<<1250, 256, 0, stream>>>(ei, row_ptr, fill, csr_src, x, dinv, xdT);
  k_p   <<<(N_NODES+RB-1)/RB, 256, 0, stream>>>(xdT, row_ptr, csr_src, dinv, P);
  k_hw2 <<<TSTEPS*BATCH*N_NODES/RB, 256, 0, stream>>>(P, dinv, W1, b1, W2, hw2d);
  k_agg <<<(TSTEPS/3)*NRB, 256, 0, stream>>>(hw2d, row_ptr, csr_src, dinv, agg2);
  k_lstm<<<NRB, 256, 0, stream>>>(agg2, WF, biasP, fc_w, fc_b, out);
}

// Round 8
// 133.454 us; speedup vs baseline: 2.7282x; 1.2971x over previous
//
#include <hip/hip_runtime.h>

#define N_NODES 5000
#define N_EDGES 160000
#define BATCH 2
#define TSTEPS 12
#define ROWS (BATCH*N_NODES)   // 10000
#define RB 16                  // rows per block (k_p / k_lstm)
#define NRB (ROWS/RB)          // 625

typedef _Float16 half8_t __attribute__((ext_vector_type(8)));
typedef float f32x4 __attribute__((ext_vector_type(4)));

// Bijective XCD swizzle for grid 5000 = 8*625 (gid = i*8 + xcd)
__device__ inline int swz5000(int gid){ return (gid & 7)*625 + (gid >> 3); }

// ---------------- k1: degree count (0..624) + WFB fragments (625..688) + permuted bias (689) ----------------
// WFB[(kt4*16+ct)*512 + lane*8 + j]:
//   kt4 0,1 : M[f][colP] with M = W2 @ W_ih^T (f = kt4*32+(lane>>4)*8+j)   [fold of layer-2 W2]
//   kt4 2,3 : W_hh[colP][k] (k = (kt4-2)*32+(lane>>4)*8+j)
//   colP = (ct&3)*64 + (ct>>2)*16 + (lane&15)   (gate-interleave permutation)
__global__ void k1(const int* __restrict__ ei, int* __restrict__ cnt,
                   const float* __restrict__ W_ih, const float* __restrict__ W_hh,
                   const float* __restrict__ W2,
                   const float* __restrict__ b_ih, const float* __restrict__ b_hh,
                   const float* __restrict__ b2,
                   _Float16* __restrict__ WFB, float* __restrict__ biasP) {
  int bid = blockIdx.x;
  if (bid < 625) {
    int e = bid*256 + threadIdx.x;
    if (e < N_EDGES) atomicAdd(&cnt[ei[N_EDGES + e]], 1);
    return;
  }
  bid -= 625;
  if (bid < 64) {
    #pragma unroll
    for (int h=0; h<2; ++h){
      int e = bid*512 + h*256 + threadIdx.x;    // 0..32767
      int kt4 = e >> 13;
      int rem = e & 8191;
      int ct  = rem >> 9;
      int le  = rem & 511;
      int lane = le >> 3, j = le & 7;
      int colP = (ct&3)*64 + (ct>>2)*16 + (lane&15);
      int kk   = (kt4&1)*32 + (lane>>4)*8 + j;
      float v;
      if (kt4 < 2){
        float s = 0.f;
        #pragma unroll 8
        for (int m=0;m<64;m++) s = fmaf(W2[kk*64+m], W_ih[colP*64+m], s);
        v = s;
      } else {
        v = W_hh[colP*64 + kk];
      }
      WFB[e] = (_Float16)v;
    }
    return;
  }
  // bias block: biasP[j] = b_ih[o]+b_hh[o]+sum_k b2[k]*W_ih[o][k], o = unpermuted col
  int jj = threadIdx.x;
  int ct = jj >> 4, c16 = jj & 15;
  int o = (ct&3)*64 + (ct>>2)*16 + c16;
  float s = b_ih[o] + b_hh[o];
  for (int k=0;k<64;k++) s = fmaf(b2[k], W_ih[o*64+k], s);
  biasP[jj] = s;
}

__global__ void k_scan(const int* __restrict__ cnt, int* __restrict__ row_ptr,
                       float* __restrict__ dinv) {
  __shared__ int sums[1024];
  int tid = threadIdx.x;
  constexpr int C = (N_NODES + 1023)/1024; // 5
  int base = tid*C;
  int local[C];
  int s = 0;
  #pragma unroll
  for (int i=0;i<C;i++){ int idx=base+i; int v=(idx<N_NODES)?cnt[idx]:0; local[i]=s; s+=v; }
  sums[tid]=s; __syncthreads();
  for (int off=1; off<1024; off<<=1) {
    int v = sums[tid];
    int add = (tid>=off)? sums[tid-off]:0;
    __syncthreads();
    sums[tid] = v + add;
    __syncthreads();
  }
  int excl = (tid>0)? sums[tid-1]:0;
  #pragma unroll
  for (int i=0;i<C;i++){ int idx=base+i; if(idx<N_NODES) row_ptr[idx]=excl+local[i]; }
  if (tid==0) row_ptr[N_NODES] = sums[1023];
  #pragma unroll
  for (int i=0;i<C;i++){ int idx=base+i; if(idx<N_NODES) dinv[idx]=rsqrtf((float)(cnt[idx]+1)); }
}

// ---------------- k2: CSR fill (blocks 0..624) + xdT build (625..1249) ----------------
__global__ void k2(const int* __restrict__ ei, const int* __restrict__ row_ptr,
                   int* __restrict__ fill, int* __restrict__ csr_src,
                   const float* __restrict__ x, const float* __restrict__ dinv,
                   float* __restrict__ xdT) {
  int bid = blockIdx.x;
  if (bid < 625) {
    int e = bid*256 + threadIdx.x;
    if (e < N_EDGES) {
      int src = ei[e], dst = ei[N_EDGES+e];
      int pos = row_ptr[dst] + atomicAdd(&fill[dst],1);
      csr_src[pos] = src;
    }
    return;
  }
  int i = (bid-625)*256 + threadIdx.x;   // 0..159999 = 5000*32
  int n = i >> 5, c = i & 31;
  xdT[i] = (c < 24) ? x[c*N_NODES + n] * dinv[n] : 0.f;
}

// ---------------- k_p: P[n][tb] = dinv[n]*(sum_src xdT[src][tb] + xdT[n][tb]) ----------------
__global__ void __launch_bounds__(256) k_p(
    const float* __restrict__ xdT,
    const int* __restrict__ row_ptr, const int* __restrict__ csr_src,
    const float* __restrict__ dinv, float* __restrict__ P)
{
  int tid = threadIdx.x;
  int wv = tid >> 6, lane = tid & 63;
  int s8 = lane >> 3, g8 = lane & 7;
  #pragma unroll
  for (int i=0;i<4;i++){
    int n = blockIdx.x*RB + wv*4 + i;
    if (n >= N_NODES) continue;
    int e0 = row_ptr[n], e1 = row_ptr[n+1];
    float ax=0.f, ay=0.f, az=0.f, aw=0.f;
    int e = e0 + s8;
    for (; e + 8 < e1; e += 16){
      int i1 = csr_src[e], i2 = csr_src[e+8];
      float4 v1 = *(const float4*)&xdT[i1*32 + g8*4];
      float4 v2 = *(const float4*)&xdT[i2*32 + g8*4];
      ax += v1.x + v2.x; ay += v1.y + v2.y;
      az += v1.z + v2.z; aw += v1.w + v2.w;
    }
    if (e < e1){
      int i1 = csr_src[e];
      float4 v1 = *(const float4*)&xdT[i1*32 + g8*4];
      ax += v1.x; ay += v1.y; az += v1.z; aw += v1.w;
    }
    #pragma unroll
    for (int m=8; m<=32; m<<=1){
      ax += __shfl_xor(ax, m, 64); ay += __shfl_xor(ay, m, 64);
      az += __shfl_xor(az, m, 64); aw += __shfl_xor(aw, m, 64);
    }
    if (s8 == 0){
      float4 sv = *(const float4*)&xdT[n*32 + g8*4];
      float dn = dinv[n];
      float4 o;
      o.x = dn*(ax + sv.x); o.y = dn*(ay + sv.y);
      o.z = dn*(az + sv.z); o.w = dn*(aw + sv.w);
      *(float4*)&P[n*32 + g8*4] = o;
    }
  }
}

// ---------------- k_g: g[(t*2+b)*N+n][f] = f16( dinv[n] * relu(p*W1[f]+b1[f]) ) ----------------
__global__ void __launch_bounds__(256) k_g(
    const float* __restrict__ P, const float* __restrict__ dinv,
    const float* __restrict__ W1, const float* __restrict__ b1,
    _Float16* __restrict__ g)
{
  int id = blockIdx.x*256 + threadIdx.x;     // 0..959999
  int nf = id >> 3, g8 = id & 7;
  int tb = nf / N_NODES;
  int n  = nf - tb*N_NODES;
  float p  = P[n*32 + (tb&1)*12 + (tb>>1)];
  float dn = dinv[n];
  half8_t o;
  #pragma unroll
  for (int j=0;j<8;j++)
    o[j] = (_Float16)(dn * fmaxf(fmaf(p, W1[g8*8+j], b1[g8*8+j]), 0.f));
  *(half8_t*)&g[(size_t)nf*64 + g8*8] = o;
}

// ---------------- k_agg: agg2[t][r][64] (f16) = D^-1/2 (A+I) g, 3 timesteps x 8 rows per block ----------------
__global__ void __launch_bounds__(256) k_agg(
    const _Float16* __restrict__ g,      // [(t*2+b)*N + n][64] f16
    const int* __restrict__ row_ptr, const int* __restrict__ csr_src,
    const float* __restrict__ dinv, _Float16* __restrict__ agg2)
{
  int tid = threadIdx.x;
  int wk = swz5000(blockIdx.x);
  int tg = wk / 1250;            // 0..3 -> timesteps 3tg..3tg+2
  int rb = wk % 1250;
  int r0 = rb*8;
  int wv = tid >> 6, lane = tid & 63;
  int s8 = lane >> 3, g8 = lane & 7;   // 8 edge-slots x 8 col-groups (half8)
  #pragma unroll
  for (int i=0;i<2;i++){
    int r = r0 + wv*2 + i;
    int b = (r >= N_NODES) ? 1 : 0;
    int n = r - b*N_NODES;
    const _Float16* h0 = g + ((size_t)(6*tg + b))*N_NODES*64;
    const _Float16* h1 = h0 + (size_t)2*N_NODES*64;
    const _Float16* h2 = h1 + (size_t)2*N_NODES*64;
    int e0 = row_ptr[n], e1 = row_ptr[n+1];
    float a0[8] = {0,0,0,0,0,0,0,0};
    float a1[8] = {0,0,0,0,0,0,0,0};
    float a2[8] = {0,0,0,0,0,0,0,0};
    int e = e0 + s8;
    for (; e + 8 < e1; e += 16){
      size_t oA = (size_t)csr_src[e]*64 + g8*8;
      size_t oB = (size_t)csr_src[e+8]*64 + g8*8;
      half8_t uA0 = *(const half8_t*)(h0 + oA);
      half8_t uA1 = *(const half8_t*)(h1 + oA);
      half8_t uA2 = *(const half8_t*)(h2 + oA);
      half8_t uB0 = *(const half8_t*)(h0 + oB);
      half8_t uB1 = *(const half8_t*)(h1 + oB);
      half8_t uB2 = *(const half8_t*)(h2 + oB);
      #pragma unroll
      for (int j=0;j<8;j++){
        a0[j] += (float)uA0[j] + (float)uB0[j];
        a1[j] += (float)uA1[j] + (float)uB1[j];
        a2[j] += (float)uA2[j] + (float)uB2[j];
      }
    }
    if (e < e1){
      size_t oA = (size_t)csr_src[e]*64 + g8*8;
      half8_t uA0 = *(const half8_t*)(h0 + oA);
      half8_t uA1 = *(const half8_t*)(h1 + oA);
      half8_t uA2 = *(const half8_t*)(h2 + oA);
      #pragma unroll
      for (int j=0;j<8;j++){
        a0[j] += (float)uA0[j]; a1[j] += (float)uA1[j]; a2[j] += (float)uA2[j];
      }
    }
    #pragma unroll
    for (int m=8; m<=32; m<<=1){
      #pragma unroll
      for (int j=0;j<8;j++){
        a0[j] += __shfl_xor(a0[j], m, 64);
        a1[j] += __shfl_xor(a1[j], m, 64);
        a2[j] += __shfl_xor(a2[j], m, 64);
      }
    }
    if (s8 == 0){
      size_t so = (size_t)n*64 + g8*8;
      half8_t sv0 = *(const half8_t*)(h0 + so);
      half8_t sv1 = *(const half8_t*)(h1 + so);
      half8_t sv2 = *(const half8_t*)(h2 + so);
      float dn = dinv[n];
      half8_t q0, q1, q2;
      #pragma unroll
      for (int j=0;j<8;j++){
        q0[j] = (_Float16)(dn*(a0[j] + (float)sv0[j]));
        q1[j] = (_Float16)(dn*(a1[j] + (float)sv1[j]));
        q2[j] = (_Float16)(dn*(a2[j] + (float)sv2[j]));
      }
      _Float16* d0 = &agg2[((size_t)(3*tg)*ROWS + r)*64 + g8*8];
      *(half8_t*)d0 = q0;
      *(half8_t*)(d0 + (size_t)ROWS*64)   = q1;
      *(half8_t*)(d0 + (size_t)2*ROWS*64) = q2;
    }
  }
}

// ---------------- k_lstm: persistent 12-step LSTM, f16 MFMA, weights in VGPRs, in-register gates ----------------
__global__ void __launch_bounds__(256) k_lstm(
    const _Float16* __restrict__ agg2,   // [t][r][64] f16
    const _Float16* __restrict__ WF,     // 4 kt4-tiles x 16 ct, permuted cols, f16
    const float* __restrict__ biasP,
    const float* __restrict__ fc_w, const float* __restrict__ fc_b,
    float* __restrict__ out)
{
  __shared__ _Float16 sH[2][RB][72];   // h, f16, double-buffered
  __shared__ float sRed[4][16];
  int tid = threadIdx.x;
  int r0 = blockIdx.x*RB;
  int wv = tid >> 6, lane = tid & 63;
  int row = lane & 15, kg = lane >> 4;
  int j = wv*16 + row;                 // this thread's h-column (gate-permuted layout)

  // weights: all 16 (kt4, ct=wv*4+i) tiles into registers, once
  half8_t Wr[4][4];
  #pragma unroll
  for (int kt4=0; kt4<4; ++kt4)
    #pragma unroll
    for (int i=0;i<4;i++)
      Wr[kt4][i] = *(const half8_t*)(WF + ((size_t)(kt4*16 + wv*4 + i))*512 + (size_t)lane*8);

  float bias[4];
  #pragma unroll
  for (int i=0;i<4;i++) bias[i] = biasP[(wv*4+i)*16 + row];

  float creg[4] = {0.f,0.f,0.f,0.f};
  float hn[4]   = {0.f,0.f,0.f,0.f};

  // prefetch agg A-tile for t=0 (already f16 fragments)
  half8_t pa0, pa1;
  {
    const _Float16* base = &agg2[((size_t)(r0 + row))*64 + kg*8];
    pa0 = *(const half8_t*)base;
    pa1 = *(const half8_t*)(base + 32);
  }

  int pb = 0;
  for (int t=0; t<TSTEPS; ++t){
    half8_t Af0 = pa0, Af1 = pa1;
    if (t+1 < TSTEPS){
      const _Float16* base = &agg2[((size_t)(t+1)*ROWS + r0 + row)*64 + kg*8];
      pa0 = *(const half8_t*)base;
      pa1 = *(const half8_t*)(base + 32);
    }
    // H-fragments (K 64..127) from LDS
    half8_t Hf0, Hf1;
    if (t > 0){
      Hf0 = *(const half8_t*)&sH[pb][row][kg*8];
      Hf1 = *(const half8_t*)&sH[pb][row][32 + kg*8];
    }
    f32x4 acc[4];
    #pragma unroll
    for (int i=0;i<4;i++){ acc[i][0]=bias[i]; acc[i][1]=bias[i]; acc[i][2]=bias[i]; acc[i][3]=bias[i]; }
    #pragma unroll
    for (int i=0;i<4;i++){
      f32x4 a = acc[i];
      a = __builtin_amdgcn_mfma_f32_16x16x32_f16(Af0, Wr[0][i], a, 0, 0, 0);
      a = __builtin_amdgcn_mfma_f32_16x16x32_f16(Af1, Wr[1][i], a, 0, 0, 0);
      if (t > 0){
        a = __builtin_amdgcn_mfma_f32_16x16x32_f16(Hf0, Wr[2][i], a, 0, 0, 0);
        a = __builtin_amdgcn_mfma_f32_16x16x32_f16(Hf1, Wr[3][i], a, 0, 0, 0);
      }
      acc[i] = a;
    }
    // in-register LSTM update: acc[i][rr] = gate_i for row kg*4+rr, col j
    #pragma unroll
    for (int rr=0;rr<4;rr++){
      float gi = acc[0][rr], gf = acc[1][rr], gg = acc[2][rr], go = acc[3][rr];
      float si = 1.f/(1.f + __expf(-gi));
      float sf = 1.f/(1.f + __expf(-gf));
      float so = 1.f/(1.f + __expf(-go));
      float tg = 2.f/(1.f + __expf(-2.f*gg)) - 1.f;
      float cn = sf*creg[rr] + si*tg;
      creg[rr] = cn;
      float tc = 2.f/(1.f + __expf(-2.f*cn)) - 1.f;
      hn[rr] = so*tc;
      sH[pb^1][kg*4+rr][j] = (_Float16)hn[rr];
    }
    __syncthreads();
    pb ^= 1;
  }
  // final projection: out[r] = sum_j h[r][j]*fc_w[j] + fc_b
  float fw = fc_w[j];
  #pragma unroll
  for (int rr=0;rr<4;rr++){
    float pv = hn[rr]*fw;
    pv += __shfl_xor(pv, 1, 64);
    pv += __shfl_xor(pv, 2, 64);
    pv += __shfl_xor(pv, 4, 64);
    pv += __shfl_xor(pv, 8, 64);
    if (row == 0) sRed[wv][kg*4+rr] = pv;
  }
  __syncthreads();
  if (tid < 16)
    out[r0 + tid] = sRed[0][tid] + sRed[1][tid] + sRed[2][tid] + sRed[3][tid] + fc_b[0];
}

extern "C" void kernel_launch(void* const* d_in, const int* in_sizes, int n_in,
                              void* d_out, int out_size, void* d_ws, size_t ws_size,
                              hipStream_t stream) {
  const float* x    = (const float*)d_in[0];
  const int*   ei   = (const int*)d_in[1];
  const float* W1   = (const float*)d_in[2];
  const float* b1   = (const float*)d_in[3];
  const float* W2   = (const float*)d_in[4];
  const float* b2   = (const float*)d_in[5];
  const float* W_ih = (const float*)d_in[6];
  const float* W_hh = (const float*)d_in[7];
  const float* b_ih = (const float*)d_in[8];
  const float* b_hh = (const float*)d_in[9];
  const float* fc_w = (const float*)d_in[10];
  const float* fc_b = (const float*)d_in[11];
  float* out = (float*)d_out;

  char* ws = (char*)d_ws;
  size_t off = 0;
  auto alloc = [&](size_t bytes)->void* { void* p = ws + off; off += (bytes + 255) & ~255ul; return p; };
  float*     dinv    = (float*)alloc(N_NODES*4);
  int*       cntfill = (int*)alloc(2*N_NODES*4);      // [0:N)=cnt, [N:2N)=fill
  int*       row_ptr = (int*)alloc((N_NODES+1)*4);
  int*       csr_src = (int*)alloc(N_EDGES*4);
  _Float16*  WFB     = (_Float16*)alloc(4*16*512*2);  // 64 KB fragments (M fold + W_hh)
  float*     biasP   = (float*)alloc(256*4);
  float*     xdT     = (float*)alloc((size_t)N_NODES*32*4);    // 640 KB
  float*     P       = (float*)alloc((size_t)N_NODES*32*4);    // 640 KB
  _Float16*  g       = (_Float16*)alloc((size_t)TSTEPS*BATCH*N_NODES*64*2); // 15.4 MB
  _Float16*  agg2    = (_Float16*)alloc((size_t)TSTEPS*ROWS*64*2);          // 15.4 MB

  int* cnt  = cntfill;
  int* fill = cntfill + N_NODES;

  hipMemsetAsync(cntfill, 0, 2*N_NODES*4, stream);

  k1    <<<690, 256, 0, stream>>>(ei, cnt, W_ih, W_hh, W2, b_ih, b_hh, b2, WFB, biasP);
  k_scan<<<1, 1024, 0, stream>>>(cnt, row_ptr, dinv);
  k2    <<<1250, 256, 0, stream>>>(ei, row_ptr, fill, csr_src, x, dinv, xdT);
  k_p   <<<(N_NODES+RB-1)/RB, 256, 0, stream>>>(xdT, row_ptr, csr_src, dinv, P);
  k_g   <<<3750, 256, 0, stream>>>(P, dinv, W1, b1, g);
  k_agg <<<5000, 256, 0, stream>>>(g, row_ptr, csr_src, dinv, agg2);
  k_lstm<<<NRB, 256, 0, stream>>>(agg2, WFB, biasP, fc_w, fc_b, out);
}

// Round 9
// 116.347 us; speedup vs baseline: 3.1293x; 1.1470x over previous
//
#include <hip/hip_runtime.h>

#define N_NODES 5000
#define N_EDGES 160000
#define BATCH 2
#define TSTEPS 12
#define ROWS (BATCH*N_NODES)   // 10000
#define RB 16                  // rows per block (k_pg / k_lstm)
#define NRB (ROWS/RB)          // 625

typedef _Float16 half8_t __attribute__((ext_vector_type(8)));
typedef float f32x4 __attribute__((ext_vector_type(4)));

// Bijective XCD swizzle for grid 5000 = 8*625 (gid = i*8 + xcd)
__device__ inline int swz5000(int gid){ return (gid & 7)*625 + (gid >> 3); }

// ---------------- k1: degree count (0..624) + WFB fragments (625..688) + permuted bias (689) ----------------
// WFB[(kt4*16+ct)*512 + lane*8 + j]:
//   kt4 0,1 : M[f][colP] with M = W2 @ W_ih^T (f = kt4*32+(lane>>4)*8+j)   [fold of layer-2 W2]
//   kt4 2,3 : W_hh[colP][k] (k = (kt4-2)*32+(lane>>4)*8+j)
//   colP = (ct&3)*64 + (ct>>2)*16 + (lane&15)   (gate-interleave permutation)
__global__ void k1(const int* __restrict__ ei, int* __restrict__ cnt,
                   const float* __restrict__ W_ih, const float* __restrict__ W_hh,
                   const float* __restrict__ W2,
                   const float* __restrict__ b_ih, const float* __restrict__ b_hh,
                   const float* __restrict__ b2,
                   _Float16* __restrict__ WFB, float* __restrict__ biasP) {
  int bid = blockIdx.x;
  if (bid < 625) {
    int e = bid*256 + threadIdx.x;
    if (e < N_EDGES) atomicAdd(&cnt[ei[N_EDGES + e]], 1);
    return;
  }
  bid -= 625;
  if (bid < 64) {
    #pragma unroll
    for (int h=0; h<2; ++h){
      int e = bid*512 + h*256 + threadIdx.x;    // 0..32767
      int kt4 = e >> 13;
      int rem = e & 8191;
      int ct  = rem >> 9;
      int le  = rem & 511;
      int lane = le >> 3, j = le & 7;
      int colP = (ct&3)*64 + (ct>>2)*16 + (lane&15);
      int kk   = (kt4&1)*32 + (lane>>4)*8 + j;
      float v;
      if (kt4 < 2){
        float s = 0.f;
        #pragma unroll 8
        for (int m=0;m<64;m++) s = fmaf(W2[kk*64+m], W_ih[colP*64+m], s);
        v = s;
      } else {
        v = W_hh[colP*64 + kk];
      }
      WFB[e] = (_Float16)v;
    }
    return;
  }
  // bias block: biasP[j] = b_ih[o]+b_hh[o]+sum_k b2[k]*W_ih[o][k], o = unpermuted col
  int jj = threadIdx.x;
  int ct = jj >> 4, c16 = jj & 15;
  int o = (ct&3)*64 + (ct>>2)*16 + c16;
  float s = b_ih[o] + b_hh[o];
  for (int k=0;k<64;k++) s = fmaf(b2[k], W_ih[o*64+k], s);
  biasP[jj] = s;
}

__global__ void k_scan(const int* __restrict__ cnt, int* __restrict__ row_ptr,
                       float* __restrict__ dinv) {
  __shared__ int sums[1024];
  int tid = threadIdx.x;
  constexpr int C = (N_NODES + 1023)/1024; // 5
  int base = tid*C;
  int local[C];
  int s = 0;
  #pragma unroll
  for (int i=0;i<C;i++){ int idx=base+i; int v=(idx<N_NODES)?cnt[idx]:0; local[i]=s; s+=v; }
  sums[tid]=s; __syncthreads();
  for (int off=1; off<1024; off<<=1) {
    int v = sums[tid];
    int add = (tid>=off)? sums[tid-off]:0;
    __syncthreads();
    sums[tid] = v + add;
    __syncthreads();
  }
  int excl = (tid>0)? sums[tid-1]:0;
  #pragma unroll
  for (int i=0;i<C;i++){ int idx=base+i; if(idx<N_NODES) row_ptr[idx]=excl+local[i]; }
  if (tid==0) row_ptr[N_NODES] = sums[1023];
  #pragma unroll
  for (int i=0;i<C;i++){ int idx=base+i; if(idx<N_NODES) dinv[idx]=rsqrtf((float)(cnt[idx]+1)); }
}

// ---------------- k2: CSR fill (blocks 0..624) + xdT build (625..1249) ----------------
__global__ void k2(const int* __restrict__ ei, const int* __restrict__ row_ptr,
                   int* __restrict__ fill, int* __restrict__ csr_src,
                   const float* __restrict__ x, const float* __restrict__ dinv,
                   float* __restrict__ xdT) {
  int bid = blockIdx.x;
  if (bid < 625) {
    int e = bid*256 + threadIdx.x;
    if (e < N_EDGES) {
      int src = ei[e], dst = ei[N_EDGES+e];
      int pos = row_ptr[dst] + atomicAdd(&fill[dst],1);
      csr_src[pos] = src;
    }
    return;
  }
  int i = (bid-625)*256 + threadIdx.x;   // 0..159999 = 5000*32
  int n = i >> 5, c = i & 31;
  xdT[i] = (c < 24) ? x[c*N_NODES + n] * dinv[n] : 0.f;
}

// ---------------- k_pg: P (layer-1 SpMV, all 24 c) + g2 production, fused ----------------
// g2[t][n][col], col = b*64 + f  (256B per (t,n) covering both batches)
// g2 = f16( dinv[n] * relu(P[n][c]*W1[f]+b1[f]) ), c = b*12+t
__global__ void __launch_bounds__(256) k_pg(
    const float* __restrict__ xdT,
    const int* __restrict__ row_ptr, const int* __restrict__ csr_src,
    const float* __restrict__ dinv,
    const float* __restrict__ W1, const float* __restrict__ b1,
    _Float16* __restrict__ g2)
{
  __shared__ float sP[RB][26];    // [node][c], c<24
  __shared__ float sW1[64], sb1[64];
  int tid = threadIdx.x;
  if (tid < 64) { sW1[tid] = W1[tid]; sb1[tid] = b1[tid]; }
  int wv = tid >> 6, lane = tid & 63;
  int s8 = lane >> 3, g8 = lane & 7;
  int n0 = blockIdx.x*RB;
  #pragma unroll
  for (int i=0;i<4;i++){
    int lr = wv*4 + i;
    int n = n0 + lr;
    if (n >= N_NODES) continue;
    int e0 = row_ptr[n], e1 = row_ptr[n+1];
    float ax=0.f, ay=0.f, az=0.f, aw=0.f;
    int e = e0 + s8;
    for (; e + 8 < e1; e += 16){
      int i1 = csr_src[e], i2 = csr_src[e+8];
      float4 v1 = *(const float4*)&xdT[i1*32 + g8*4];
      float4 v2 = *(const float4*)&xdT[i2*32 + g8*4];
      ax += v1.x + v2.x; ay += v1.y + v2.y;
      az += v1.z + v2.z; aw += v1.w + v2.w;
    }
    if (e < e1){
      int i1 = csr_src[e];
      float4 v1 = *(const float4*)&xdT[i1*32 + g8*4];
      ax += v1.x; ay += v1.y; az += v1.z; aw += v1.w;
    }
    #pragma unroll
    for (int m=8; m<=32; m<<=1){
      ax += __shfl_xor(ax, m, 64); ay += __shfl_xor(ay, m, 64);
      az += __shfl_xor(az, m, 64); aw += __shfl_xor(aw, m, 64);
    }
    if (s8 == 0 && g8 < 6){
      float4 sv = *(const float4*)&xdT[n*32 + g8*4];
      float dn = dinv[n];
      sP[lr][g8*4+0] = dn*(ax + sv.x);
      sP[lr][g8*4+1] = dn*(ay + sv.y);
      sP[lr][g8*4+2] = dn*(az + sv.z);
      sP[lr][g8*4+3] = dn*(aw + sv.w);
    }
  }
  __syncthreads();
  // epilogue: 16 nodes x 12 t x 16 col-octets = 3072 half8 writes
  for (int u = tid; u < RB*12*16; u += 256){
    int node = u / 192;
    int rem  = u - node*192;
    int t  = rem >> 4;
    int oc = rem & 15;
    int b  = oc >> 3, f8 = oc & 7;
    int n = n0 + node;
    if (n >= N_NODES) continue;
    float p  = sP[node][b*12 + t];
    float dn = dinv[n];
    half8_t o;
    #pragma unroll
    for (int j=0;j<8;j++)
      o[j] = (_Float16)(dn * fmaxf(fmaf(p, sW1[f8*8+j], sb1[f8*8+j]), 0.f));
    *(half8_t*)&g2[((size_t)t*N_NODES + n)*128 + oc*8] = o;
  }
}

// ---------------- k_agg: agg2[t][r][64] (f16) = D^-1/2 (A+I) g2 ----------------
// One wave per node; 16 lanes cover both batches (256B per edge-t request); 3 t per block.
__global__ void __launch_bounds__(256) k_agg(
    const _Float16* __restrict__ g2,     // [t][n][128] f16
    const int* __restrict__ row_ptr, const int* __restrict__ csr_src,
    const float* __restrict__ dinv, _Float16* __restrict__ agg2)
{
  int tid = threadIdx.x;
  int wk = swz5000(blockIdx.x);
  int tg = wk / 1250;            // 0..3 -> timesteps 3tg..3tg+2
  int nb = wk % 1250;
  int wv = tid >> 6, lane = tid & 63;
  int n = nb*4 + wv;             // one node per wave, always < 5000
  int slot = lane >> 4;          // 4 edge slots
  int l16 = lane & 15;           // col octet: b = l16>>3, f8 = l16&7
  int b = l16 >> 3, f8 = l16 & 7;
  const _Float16* gA = g2 + (size_t)(3*tg)*N_NODES*128;
  const size_t slab = (size_t)N_NODES*128;
  int e0 = row_ptr[n], e1 = row_ptr[n+1];
  float a0[8]={0,0,0,0,0,0,0,0}, a1[8]={0,0,0,0,0,0,0,0}, a2[8]={0,0,0,0,0,0,0,0};
  int e = e0 + slot;
  for (; e + 4 < e1; e += 8){
    size_t oA = (size_t)csr_src[e]*128 + l16*8;
    size_t oB = (size_t)csr_src[e+4]*128 + l16*8;
    half8_t uA0 = *(const half8_t*)(gA + oA);
    half8_t uB0 = *(const half8_t*)(gA + oB);
    half8_t uA1 = *(const half8_t*)(gA + slab + oA);
    half8_t uB1 = *(const half8_t*)(gA + slab + oB);
    half8_t uA2 = *(const half8_t*)(gA + 2*slab + oA);
    half8_t uB2 = *(const half8_t*)(gA + 2*slab + oB);
    half8_t s0 = uA0 + uB0;          // v_pk_add_f16 (g ~0.01-scale: err negligible)
    half8_t s1 = uA1 + uB1;
    half8_t s2 = uA2 + uB2;
    #pragma unroll
    for (int j=0;j<8;j++){
      a0[j] += (float)s0[j]; a1[j] += (float)s1[j]; a2[j] += (float)s2[j];
    }
  }
  for (; e < e1; e += 4){
    size_t oA = (size_t)csr_src[e]*128 + l16*8;
    half8_t uA0 = *(const half8_t*)(gA + oA);
    half8_t uA1 = *(const half8_t*)(gA + slab + oA);
    half8_t uA2 = *(const half8_t*)(gA + 2*slab + oA);
    #pragma unroll
    for (int j=0;j<8;j++){
      a0[j] += (float)uA0[j]; a1[j] += (float)uA1[j]; a2[j] += (float)uA2[j];
    }
  }
  #pragma unroll
  for (int m=16; m<=32; m<<=1){
    #pragma unroll
    for (int j=0;j<8;j++){
      a0[j] += __shfl_xor(a0[j], m, 64);
      a1[j] += __shfl_xor(a1[j], m, 64);
      a2[j] += __shfl_xor(a2[j], m, 64);
    }
  }
  if (slot == 0){
    size_t so = (size_t)n*128 + l16*8;
    half8_t sv0 = *(const half8_t*)(gA + so);
    half8_t sv1 = *(const half8_t*)(gA + slab + so);
    half8_t sv2 = *(const half8_t*)(gA + 2*slab + so);
    float dn = dinv[n];
    half8_t q0, q1, q2;
    #pragma unroll
    for (int j=0;j<8;j++){
      q0[j] = (_Float16)(dn*(a0[j] + (float)sv0[j]));
      q1[j] = (_Float16)(dn*(a1[j] + (float)sv1[j]));
      q2[j] = (_Float16)(dn*(a2[j] + (float)sv2[j]));
    }
    size_t r64 = ((size_t)(3*tg)*ROWS + b*N_NODES + n)*64 + f8*8;
    *(half8_t*)&agg2[r64] = q0;
    *(half8_t*)&agg2[r64 + (size_t)ROWS*64]   = q1;
    *(half8_t*)&agg2[r64 + (size_t)2*ROWS*64] = q2;
  }
}

// ---------------- k_lstm: persistent 12-step LSTM, f16 MFMA, weights in VGPRs, in-register gates ----------------
__global__ void __launch_bounds__(256) k_lstm(
    const _Float16* __restrict__ agg2,   // [t][r][64] f16
    const _Float16* __restrict__ WF,     // 4 kt4-tiles x 16 ct, permuted cols, f16
    const float* __restrict__ biasP,
    const float* __restrict__ fc_w, const float* __restrict__ fc_b,
    float* __restrict__ out)
{
  __shared__ _Float16 sH[2][RB][72];   // h, f16, double-buffered
  __shared__ float sRed[4][16];
  int tid = threadIdx.x;
  int r0 = blockIdx.x*RB;
  int wv = tid >> 6, lane = tid & 63;
  int row = lane & 15, kg = lane >> 4;
  int j = wv*16 + row;                 // this thread's h-column (gate-permuted layout)

  // weights: all 16 (kt4, ct=wv*4+i) tiles into registers, once
  half8_t Wr[4][4];
  #pragma unroll
  for (int kt4=0; kt4<4; ++kt4)
    #pragma unroll
    for (int i=0;i<4;i++)
      Wr[kt4][i] = *(const half8_t*)(WF + ((size_t)(kt4*16 + wv*4 + i))*512 + (size_t)lane*8);

  float bias[4];
  #pragma unroll
  for (int i=0;i<4;i++) bias[i] = biasP[(wv*4+i)*16 + row];

  float creg[4] = {0.f,0.f,0.f,0.f};
  float hn[4]   = {0.f,0.f,0.f,0.f};

  // prefetch agg A-tile for t=0 (already f16 fragments)
  half8_t pa0, pa1;
  {
    const _Float16* base = &agg2[((size_t)(r0 + row))*64 + kg*8];
    pa0 = *(const half8_t*)base;
    pa1 = *(const half8_t*)(base + 32);
  }

  int pb = 0;
  for (int t=0; t<TSTEPS; ++t){
    half8_t Af0 = pa0, Af1 = pa1;
    if (t+1 < TSTEPS){
      const _Float16* base = &agg2[((size_t)(t+1)*ROWS + r0 + row)*64 + kg*8];
      pa0 = *(const half8_t*)base;
      pa1 = *(const half8_t*)(base + 32);
    }
    // H-fragments (K 64..127) from LDS
    half8_t Hf0, Hf1;
    if (t > 0){
      Hf0 = *(const half8_t*)&sH[pb][row][kg*8];
      Hf1 = *(const half8_t*)&sH[pb][row][32 + kg*8];
    }
    f32x4 acc[4];
    #pragma unroll
    for (int i=0;i<4;i++){ acc[i][0]=bias[i]; acc[i][1]=bias[i]; acc[i][2]=bias[i]; acc[i][3]=bias[i]; }
    #pragma unroll
    for (int i=0;i<4;i++){
      f32x4 a = acc[i];
      a = __builtin_amdgcn_mfma_f32_16x16x32_f16(Af0, Wr[0][i], a, 0, 0, 0);
      a = __builtin_amdgcn_mfma_f32_16x16x32_f16(Af1, Wr[1][i], a, 0, 0, 0);
      if (t > 0){
        a = __builtin_amdgcn_mfma_f32_16x16x32_f16(Hf0, Wr[2][i], a, 0, 0, 0);
        a = __builtin_amdgcn_mfma_f32_16x16x32_f16(Hf1, Wr[3][i], a, 0, 0, 0);
      }
      acc[i] = a;
    }
    // in-register LSTM update: acc[i][rr] = gate_i for row kg*4+rr, col j
    #pragma unroll
    for (int rr=0;rr<4;rr++){
      float gi = acc[0][rr], gf = acc[1][rr], gg = acc[2][rr], go = acc[3][rr];
      float si = 1.f/(1.f + __expf(-gi));
      float sf = 1.f/(1.f + __expf(-gf));
      float so = 1.f/(1.f + __expf(-go));
      float tg = 2.f/(1.f + __expf(-2.f*gg)) - 1.f;
      float cn = sf*creg[rr] + si*tg;
      creg[rr] = cn;
      float tc = 2.f/(1.f + __expf(-2.f*cn)) - 1.f;
      hn[rr] = so*tc;
      sH[pb^1][kg*4+rr][j] = (_Float16)hn[rr];
    }
    __syncthreads();
    pb ^= 1;
  }
  // final projection: out[r] = sum_j h[r][j]*fc_w[j] + fc_b
  float fw = fc_w[j];
  #pragma unroll
  for (int rr=0;rr<4;rr++){
    float pv = hn[rr]*fw;
    pv += __shfl_xor(pv, 1, 64);
    pv += __shfl_xor(pv, 2, 64);
    pv += __shfl_xor(pv, 4, 64);
    pv += __shfl_xor(pv, 8, 64);
    if (row == 0) sRed[wv][kg*4+rr] = pv;
  }
  __syncthreads();
  if (tid < 16)
    out[r0 + tid] = sRed[0][tid] + sRed[1][tid] + sRed[2][tid] + sRed[3][tid] + fc_b[0];
}

extern "C" void kernel_launch(void* const* d_in, const int* in_sizes, int n_in,
                              void* d_out, int out_size, void* d_ws, size_t ws_size,
                              hipStream_t stream) {
  const float* x    = (const float*)d_in[0];
  const int*   ei   = (const int*)d_in[1];
  const float* W1   = (const float*)d_in[2];
  const float* b1   = (const float*)d_in[3];
  const float* W2   = (const float*)d_in[4];
  const float* b2   = (const float*)d_in[5];
  const float* W_ih = (const float*)d_in[6];
  const float* W_hh = (const float*)d_in[7];
  const float* b_ih = (const float*)d_in[8];
  const float* b_hh = (const float*)d_in[9];
  const float* fc_w = (const float*)d_in[10];
  const float* fc_b = (const float*)d_in[11];
  float* out = (float*)d_out;

  char* ws = (char*)d_ws;
  size_t off = 0;
  auto alloc = [&](size_t bytes)->void* { void* p = ws + off; off += (bytes + 255) & ~255ul; return p; };
  float*     dinv    = (float*)alloc(N_NODES*4);
  int*       cntfill = (int*)alloc(2*N_NODES*4);      // [0:N)=cnt, [N:2N)=fill
  int*       row_ptr = (int*)alloc((N_NODES+1)*4);
  int*       csr_src = (int*)alloc(N_EDGES*4);
  _Float16*  WFB     = (_Float16*)alloc(4*16*512*2);  // 64 KB fragments (M fold + W_hh)
  float*     biasP   = (float*)alloc(256*4);
  float*     xdT     = (float*)alloc((size_t)N_NODES*32*4);    // 640 KB
  _Float16*  g2      = (_Float16*)alloc((size_t)TSTEPS*N_NODES*128*2); // 15.4 MB, [t][n][b*64+f]
  _Float16*  agg2    = (_Float16*)alloc((size_t)TSTEPS*ROWS*64*2);     // 15.4 MB

  int* cnt  = cntfill;
  int* fill = cntfill + N_NODES;

  hipMemsetAsync(cntfill, 0, 2*N_NODES*4, stream);

  k1    <<<690, 256, 0, stream>>>(ei, cnt, W_ih, W_hh, W2, b_ih, b_hh, b2, WFB, biasP);
  k_scan<<<1, 1024, 0, stream>>>(cnt, row_ptr, dinv);
  k2    <<<1250, 256, 0, stream>>>(ei, row_ptr, fill, csr_src, x, dinv, xdT);
  k_pg  <<<(N_NODES+RB-1)/RB, 256, 0, stream>>>(xdT, row_ptr, csr_src, dinv, W1, b1, g2);
  k_agg <<<5000, 256, 0, stream>>>(g2, row_ptr, csr_src, dinv, agg2);
  k_lstm<<<NRB, 256, 0, stream>>>(agg2, WFB, biasP, fc_w, fc_b, out);
}